// Round 8
// baseline (108.294 us; speedup 1.0000x reference)
//
#include <hip/hip_runtime.h>
#include <hip/hip_bf16.h>
#include <math.h>

#define HH 128
#define NN 64
#define LL 4096
#define BB 8
#define NFFT 8192
#define KSTR 4160  // per-h stride of permuted K spectrum (4097 used, padded)

// stage1 grid partitions, dispatched in this order (cauchy first = critical path,
// memory-bound transpose/skip blocks backfill and overlap on the other wave slots)
#define CAU_BLOCKS 512    // 128 h x 4 l-blocks; each thread does 4 l-points
#define TRU_BLOCKS 4096   // 8 b x 4 h-tiles x 128 l-tiles (32x32)
#define SKP_BLOCKS 8192   // 4 rows/block (1 row per 64-lane wave)

__device__ __forceinline__ float2 cmul(float2 a, float2 b) {
    return make_float2(a.x * b.x - a.y * b.y, a.x * b.y + a.y * b.x);
}
__device__ __forceinline__ float2 cadd(float2 a, float2 b) {
    return make_float2(a.x + b.x, a.y + b.y);
}
__device__ __forceinline__ float2 csub(float2 a, float2 b) {
    return make_float2(a.x - b.x, a.y - b.y);
}
__device__ __forceinline__ int brev13(int x) { return (int)(__brev((unsigned)x) >> 19); }
// conv/kfreq shared frequency-index map (low6<->high6 swizzle, bank-friendly LDS)
__device__ __forceinline__ int kkmap(int t) {
    return (t < 4096) ? (((t & 63) << 6) | (t >> 6)) : 4096;
}

// Twiddle via HW sin/cos (REVOLUTIONS, arg in [0,0.5) -> no range reduction).
__device__ __forceinline__ float2 twid(float rev, float sg) {
    return make_float2(__builtin_amdgcn_cosf(rev), sg * __builtin_amdgcn_sinf(rev));
}

// ---- Fused radix-4 passes (== two radix-2 stages; preserves bitrev semantics) ----

// DIF fused pair: stage half=2M then half=M. Input natural at pass entry.
template <int M>
__device__ __forceinline__ void dif_f4(float2* d, int N, int tid, int nt, float sg) {
    const float inv2m = 1.0f / (2.0f * (float)M);
    const float inv4m = 1.0f / (4.0f * (float)M);
    for (int q = tid; q < (N >> 2); q += nt) {
        int j = q & (M - 1);
        int i0 = ((q & ~(M - 1)) << 2) + j;
        float2 x0 = d[i0], x1 = d[i0 + M], x2 = d[i0 + 2 * M], x3 = d[i0 + 3 * M];
        float jf = (float)j;
        float2 wB = twid(jf * inv4m, sg);
        float2 wA = twid(jf * inv2m, sg);
        float2 a0 = cadd(x0, x2);
        float2 a2 = cmul(wB, csub(x0, x2));
        float2 a1 = cadd(x1, x3);
        float2 t = cmul(wB, csub(x1, x3));
        float2 a3 = make_float2(-sg * t.y, sg * t.x);  // (i*sg)*t
        d[i0] = cadd(a0, a1);
        d[i0 + M] = cmul(wA, csub(a0, a1));
        d[i0 + 2 * M] = cadd(a2, a3);
        d[i0 + 3 * M] = cmul(wA, csub(a2, a3));
    }
    __syncthreads();
}

// DIT fused pair: stage half=M then half=2M. Input bitrev at pass entry.
template <int M>
__device__ __forceinline__ void dit_f4(float2* d, int N, int tid, int nt, float sg) {
    const float inv2m = 1.0f / (2.0f * (float)M);
    const float inv4m = 1.0f / (4.0f * (float)M);
    for (int q = tid; q < (N >> 2); q += nt) {
        int j = q & (M - 1);
        int i0 = ((q & ~(M - 1)) << 2) + j;
        float2 x0 = d[i0], x1 = d[i0 + M], x2 = d[i0 + 2 * M], x3 = d[i0 + 3 * M];
        float jf = (float)j;
        float2 wA = twid(jf * inv2m, sg);
        float2 wB = twid(jf * inv4m, sg);
        float2 t0 = cmul(wA, x1), t1 = cmul(wA, x3);
        float2 a0 = cadd(x0, t0), a1 = csub(x0, t0);
        float2 a2 = cadd(x2, t1), a3 = csub(x2, t1);
        float2 u = cmul(wB, a2), v = cmul(wB, a3);
        float2 vi = make_float2(-sg * v.y, sg * v.x);  // (i*sg)*v
        d[i0] = cadd(a0, u);
        d[i0 + 2 * M] = csub(a0, u);
        d[i0 + M] = cadd(a1, vi);
        d[i0 + 3 * M] = csub(a1, vi);
    }
    __syncthreads();
}

// Stage 1 (fused): [cauchy at_roots, 4 pts/thread] ++ [transpose u->ut] ++ [skip=u@D].
__global__ __launch_bounds__(256) void stage1_kernel(
    const float* __restrict__ u,
    const float* __restrict__ B_ri, const float* __restrict__ C_ri,
    const float* __restrict__ D,
    const float* __restrict__ Lambda_ri, const float* __restrict__ P_ri,
    const float* __restrict__ step,
    float2* __restrict__ at_g, float* __restrict__ ut, float* __restrict__ skip) {
    __shared__ float4 smem4[264];  // union: cauchy tables [64*3] 3072B / transpose tile 4224B
    const int bid = blockIdx.x;
    const int tid = threadIdx.x;

    if (bid < CAU_BLOCKS) {
        // ---- Cauchy: h = bid>>2; thread handles l = lbase + p*256, p=0..3.
        // 3 broadcast ds_read_b128 per n feed 4 points of VALU (amortized 4x vs r6).
        const int h = bid >> 2;
        if (tid < NN) {
            int n = tid;
            float2 C = ((const float2*)C_ri)[h * NN + n];
            float2 Bv = ((const float2*)B_ri)[h * NN + n];
            float2 P = ((const float2*)P_ri)[h * NN + n];
            float2 lam = ((const float2*)Lambda_ri)[h * NN + n];
            float2 Cc = make_float2(C.x, -C.y);
            float2 Pc = make_float2(P.x, -P.y);
            float2 v00 = cmul(Cc, Bv);
            float2 v01 = cmul(Cc, P);
            float2 v10 = cmul(Pc, Bv);
            float2 v11 = cmul(Pc, P);
            smem4[n * 3 + 0] = make_float4(lam.x, lam.y, v00.x, v00.y);
            smem4[n * 3 + 1] = make_float4(v01.x, v01.y, v10.x, v10.y);
            smem4[n * 3 + 2] = make_float4(v11.x, v11.y, 0.f, 0.f);
        }
        __syncthreads();

        const int lbase = ((bid & 3) << 10) | tid;
        const float two_over_step = 2.0f / step[0];
        float gr[4], gi[4], ccx[4], ccy[4];
#pragma unroll
        for (int p = 0; p < 4; ++p) {
            int l = lbase + p * 256;
            // z = exp(-2*pi*i*l/L). libm sincosf: at l=2048 the fp32-pi inexactness
            // keeps 1+z away from exactly 0 (matches reference behavior). DO NOT
            // replace with HW sin/cos here.
            double th = -6.283185307179586476925286766559 * (double)l / (double)LL;
            float sn, cs;
            sincosf((float)th, &sn, &cs);
            float dr = 1.0f + cs, di = sn;  // 1+z
            float inv = __builtin_amdgcn_rcpf(dr * dr + di * di);
            float nr = 1.0f - cs, ni = -sn;  // 1-z
            gr[p] = two_over_step * (nr * dr + ni * di) * inv;
            gi[p] = two_over_step * (ni * dr - nr * di) * inv;
            ccx[p] = 2.0f * dr * inv;
            ccy[p] = -2.0f * di * inv;
        }

        float2 k00[4], k01[4], k10[4], k11[4];
#pragma unroll
        for (int p = 0; p < 4; ++p) {
            k00[p] = make_float2(0.f, 0.f);
            k01[p] = make_float2(0.f, 0.f);
            k10[p] = make_float2(0.f, 0.f);
            k11[p] = make_float2(0.f, 0.f);
        }
#pragma unroll 2
        for (int n = 0; n < NN; ++n) {
            float4 tA = smem4[n * 3 + 0];
            float4 tB = smem4[n * 3 + 1];
            float4 tC = smem4[n * 3 + 2];
#pragma unroll
            for (int p = 0; p < 4; ++p) {
                float ar = gr[p] - tA.x, ai = gi[p] - tA.y;
                float id = __builtin_amdgcn_rcpf(ar * ar + ai * ai);
                float2 r = make_float2(ar * id, -ai * id);  // 1/(g-lambda)
                k00[p] = cadd(k00[p], cmul(make_float2(tA.z, tA.w), r));
                k01[p] = cadd(k01[p], cmul(make_float2(tB.x, tB.y), r));
                k10[p] = cadd(k10[p], cmul(make_float2(tB.z, tB.w), r));
                k11[p] = cadd(k11[p], cmul(make_float2(tC.x, tC.y), r));
            }
        }
#pragma unroll
        for (int p = 0; p < 4; ++p) {
            float wr = 1.0f + k11[p].x, wi = k11[p].y;
            float iw = __builtin_amdgcn_rcpf(wr * wr + wi * wi);
            float2 winv = make_float2(wr * iw, -wi * iw);
            float2 t = cmul(cmul(k01[p], winv), k10[p]);
            float2 at = cmul(make_float2(ccx[p], ccy[p]),
                             make_float2(k00[p].x - t.x, k00[p].y - t.y));
            at_g[(size_t)h * LL + lbase + p * 256] = at;
        }
    } else if (bid < CAU_BLOCKS + TRU_BLOCKS) {
        // ---- Transpose: u [B,L,H] -> ut [B,H,L], 32x32 tiles ----
        float* tile = (float*)smem4;  // [32][33]
        int tb = bid - CAU_BLOCKS;
        int b = tb >> 9;
        int h0 = ((tb >> 7) & 3) * 32;
        int l0 = (tb & 127) * 32;
        int tx = tid & 31, ty = tid >> 5;  // ty 0..7
        const float* up = u + (size_t)b * LL * HH;
        float* utp = ut + (size_t)b * HH * LL;
        for (int i = ty; i < 32; i += 8)
            tile[i * 33 + tx] = up[(size_t)(l0 + i) * HH + h0 + tx];
        __syncthreads();
        for (int i = ty; i < 32; i += 8)
            utp[(size_t)(h0 + i) * LL + l0 + tx] = tile[tx * 33 + i];
    } else {
        // ---- Skip: skip[row] = sum_h u[row,h]*D[h]; 1 row per 64-lane wave ----
        int sb = bid - (CAU_BLOCKS + TRU_BLOCKS);  // [0, 8192)
        int wid = tid >> 6, lane = tid & 63;
        int row = sb * 4 + wid;
        const float* ur = u + (size_t)row * HH;
        float v = ur[lane] * D[lane] + ur[lane + 64] * D[lane + 64];
        for (int off = 32; off > 0; off >>= 1) v += __shfl_down(v, off, 64);
        if (lane == 0) skip[row] = v;
    }
}

// Kernel A2: per h — scatter-load at -> IFFT4096 -> fused {scale + pad + head-r2}
// -> FFT8192 (remaining 12 stages) -> store permuted K spectrum KfP[h][t] = K_h(kk(t)).
__global__ __launch_bounds__(1024) void kfreq_kernel(const float2* __restrict__ at_g,
                                                     float2* __restrict__ KfP) {
    __shared__ float2 sm[NFFT];  // 64 KB
    const int h = blockIdx.x;
    const int tid = threadIdx.x;
    const float2* ap = at_g + (size_t)h * LL;
#pragma unroll
    for (int it = 0; it < 4; ++it) {
        int t = tid + it * 1024;
        int l = ((t & 63) << 6) | (t >> 6);     // low6<->high6 swap
        sm[__brev((unsigned)l) >> 20] = ap[l];  // LDS slot low bits vary per lane
    }
    __syncthreads();

    // inverse FFT 4096 (bitrev in -> natural out)
    dit_f4<1>(sm, 4096, tid, 1024, +1.f);
    dit_f4<4>(sm, 4096, tid, 1024, +1.f);
    dit_f4<16>(sm, 4096, tid, 1024, +1.f);
    dit_f4<64>(sm, 4096, tid, 1024, +1.f);
    dit_f4<256>(sm, 4096, tid, 1024, +1.f);
    dit_f4<1024>(sm, 4096, tid, 1024, +1.f);

    // fused: k = real/4096, zero-pad, and head radix-2 DIF stage (upper half = w*k)
    const float inv8192 = 1.0f / 8192.0f;
    for (int t = tid; t < 4096; t += 1024) {
        float kv = sm[t].x * (1.0f / 4096.0f);
        float2 w = twid((float)t * inv8192, -1.f);
        sm[t] = make_float2(kv, 0.f);
        sm[t + 4096] = make_float2(kv * w.x, kv * w.y);
    }
    __syncthreads();

    // forward FFT 8192, remaining stages (natural in -> bitrev13 out)
    dif_f4<1024>(sm, 8192, tid, 1024, -1.f);
    dif_f4<256>(sm, 8192, tid, 1024, -1.f);
    dif_f4<64>(sm, 8192, tid, 1024, -1.f);
    dif_f4<16>(sm, 8192, tid, 1024, -1.f);
    dif_f4<4>(sm, 8192, tid, 1024, -1.f);
    dif_f4<1>(sm, 8192, tid, 1024, -1.f);

    // permuted store: conv reads K linearly in t (coalesced); LDS gather is cheap here
    float2* kfp = KfP + (size_t)h * KSTR;
    for (int t = tid; t <= 4096; t += 1024) kfp[t] = sm[brev13(kkmap(t))];
}

// Kernel C: two-for-one conv — pack (h0,h1) as re+im; fused {load + head-r2};
// fwd FFT (12 remaining stages); pointwise with coalesced permuted K; inv FFT
// (12 stages) with fused {tail-r2 + scale + store}.
__global__ __launch_bounds__(1024) void conv_fft_kernel(const float* __restrict__ ut,
                                                        const float2* __restrict__ KfP,
                                                        float* __restrict__ yt) {
    __shared__ float2 sm[NFFT];  // 64 KB
    const int b = blockIdx.x >> 6;
    const int c = blockIdx.x & 63;
    const int h0 = 2 * c, h1 = 2 * c + 1;
    const int tid = threadIdx.x;
    const float* up0 = ut + ((size_t)b * HH + h0) * LL;
    const float* up1 = ut + ((size_t)b * HH + h1) * LL;
    const float inv8192 = 1.0f / 8192.0f;

    // fused load + head radix-2 DIF stage (upper half of input is zero)
    for (int i = tid; i < 4096; i += 1024) {
        float2 a = make_float2(up0[i], up1[i]);
        float2 w = twid((float)i * inv8192, -1.f);
        sm[i] = a;
        sm[i + 4096] = cmul(w, a);
    }
    __syncthreads();

    dif_f4<1024>(sm, 8192, tid, 1024, -1.f);
    dif_f4<256>(sm, 8192, tid, 1024, -1.f);
    dif_f4<64>(sm, 8192, tid, 1024, -1.f);
    dif_f4<16>(sm, 8192, tid, 1024, -1.f);
    dif_f4<4>(sm, 8192, tid, 1024, -1.f);
    dif_f4<1>(sm, 8192, tid, 1024, -1.f);

    // Pointwise in bitrev order; each thread-iteration owns conjugate pair (k, N-k).
    // K reads are linear in t (coalesced); only K[p] is needed (Hermitian identity).
    const float2* kf0 = KfP + (size_t)h0 * KSTR;
    const float2* kf1 = KfP + (size_t)h1 * KSTR;
    for (int t = tid; t <= 4096; t += 1024) {
        int kk = kkmap(t);
        bool self = (kk == 0) || (kk == 4096);
        int p = brev13(kk);
        int q = self ? p : brev13(NFFT - kk);
        float2 K0 = kf0[t];
        float2 K1 = kf1[t];
        float2 Zp = sm[p];
        float2 Zq = sm[q];
        float2 U0 = make_float2(0.5f * (Zp.x + Zq.x), 0.5f * (Zp.y - Zq.y));
        float2 U1 = make_float2(0.5f * (Zp.y + Zq.y), 0.5f * (Zq.x - Zp.x));
        float2 A = cmul(U0, K0);
        float2 C = cmul(U1, K1);
        sm[p] = make_float2(A.x - C.y, A.y + C.x);             // W[k]   = A + iC
        if (!self) sm[q] = make_float2(A.x + C.y, C.x - A.y);  // W[N-k] = conj(A - iC)
    }
    __syncthreads();

    dit_f4<1>(sm, 8192, tid, 1024, +1.f);
    dit_f4<4>(sm, 8192, tid, 1024, +1.f);
    dit_f4<16>(sm, 8192, tid, 1024, +1.f);
    dit_f4<64>(sm, 8192, tid, 1024, +1.f);
    dit_f4<256>(sm, 8192, tid, 1024, +1.f);
    dit_f4<1024>(sm, 8192, tid, 1024, +1.f);

    // fused tail radix-2 DIT stage + 1/N scale + store (only first 4096 samples kept)
    float* yp0 = yt + ((size_t)b * HH + h0) * LL;
    float* yp1 = yt + ((size_t)b * HH + h1) * LL;
    const float invN = 1.0f / (float)NFFT;
    for (int x = tid; x < 4096; x += 1024) {
        float2 w = twid((float)x * inv8192, +1.f);
        float2 a = sm[x];
        float2 bb = cmul(w, sm[x + 4096]);
        yp0[x] = (a.x + bb.x) * invN;
        yp1[x] = (a.y + bb.y) * invN;
    }
}

// Kernel D: transpose yt [B,H,L] -> y [B,L,H], add broadcast skip[b,l]
__global__ __launch_bounds__(256) void transpose_y_kernel(const float* __restrict__ yt,
                                                          const float* __restrict__ skip,
                                                          float* __restrict__ y) {
    __shared__ float tile[32][33];
    int b = blockIdx.z;
    int h0 = blockIdx.x * 32, l0 = blockIdx.y * 32;
    const float* ytp = yt + (size_t)b * HH * LL;
    const float* skp = skip + (size_t)b * LL;
    float* yp = y + (size_t)b * LL * HH;
    for (int i = threadIdx.y; i < 32; i += 8)
        tile[i][threadIdx.x] = ytp[(size_t)(h0 + i) * LL + l0 + threadIdx.x];
    __syncthreads();
    for (int i = threadIdx.y; i < 32; i += 8) {
        size_t idx = (size_t)(l0 + i) * HH + h0 + threadIdx.x;
        yp[idx] = tile[threadIdx.x][i] + skp[l0 + i];
    }
}

extern "C" void kernel_launch(void* const* d_in, const int* in_sizes, int n_in,
                              void* d_out, int out_size, void* d_ws, size_t ws_size,
                              hipStream_t stream) {
    const float* u = (const float*)d_in[0];
    const float* B_ri = (const float*)d_in[1];
    const float* C_ri = (const float*)d_in[2];
    const float* D = (const float*)d_in[3];
    const float* Lambda_ri = (const float*)d_in[4];
    const float* P_ri = (const float*)d_in[5];
    const float* step = (const float*)d_in[6];
    float* out = (float*)d_out;

    char* ws = (char*)d_ws;
    float2* KfP = (float2*)ws;                             // ~4.2 MB @ 0
    float* skip = (float*)(ws + (size_t)6 * 1024 * 1024);  // 128 KB @ 6 MB
    float* ut = (float*)(ws + (size_t)8 * 1024 * 1024);    // 16 MB @ 8 MB
    float* yt = (float*)(ws + (size_t)24 * 1024 * 1024);   // 16 MB @ 24 MB
    // at_g aliases yt: written by stage1, consumed by kfreq before conv writes yt.
    float2* at_g = (float2*)yt;                            // 4 MB

    stage1_kernel<<<dim3(CAU_BLOCKS + TRU_BLOCKS + SKP_BLOCKS), dim3(256), 0, stream>>>(
        u, B_ri, C_ri, D, Lambda_ri, P_ri, step, at_g, ut, skip);
    kfreq_kernel<<<dim3(HH), dim3(1024), 0, stream>>>(at_g, KfP);
    conv_fft_kernel<<<dim3(BB * HH / 2), dim3(1024), 0, stream>>>(ut, KfP, yt);
    transpose_y_kernel<<<dim3(HH / 32, LL / 32, BB), dim3(32, 8), 0, stream>>>(yt, skip, out);
}

// Round 9
// 91.964 us; speedup vs baseline: 1.1776x; 1.1776x over previous
//
#include <hip/hip_runtime.h>
#include <hip/hip_bf16.h>
#include <math.h>

#define HH 128
#define NN 64
#define LL 4096
#define BB 8
#define NFFT 8192
#define KSTR 4160  // per-h stride of permuted K spectrum (4097 used, padded)

// stage1 grid partitions, dispatched in this order (cauchy first = critical path,
// memory-bound transpose/skip blocks backfill and overlap on the other wave slots)
#define CAU_BLOCKS 1024   // 128 h x 8 l-blocks; each thread does 2 l-points
#define TRU_BLOCKS 4096   // 8 b x 4 h-tiles x 128 l-tiles (32x32)
#define SKP_BLOCKS 8192   // 4 rows/block (1 row per 64-lane wave)

__device__ __forceinline__ float2 cmul(float2 a, float2 b) {
    return make_float2(a.x * b.x - a.y * b.y, a.x * b.y + a.y * b.x);
}
__device__ __forceinline__ float2 cadd(float2 a, float2 b) {
    return make_float2(a.x + b.x, a.y + b.y);
}
__device__ __forceinline__ float2 csub(float2 a, float2 b) {
    return make_float2(a.x - b.x, a.y - b.y);
}
__device__ __forceinline__ int brev13(int x) { return (int)(__brev((unsigned)x) >> 19); }
// conv/kfreq shared frequency-index map (low6<->high6 swizzle, bank-friendly LDS)
__device__ __forceinline__ int kkmap(int t) {
    return (t < 4096) ? (((t & 63) << 6) | (t >> 6)) : 4096;
}

// Twiddle via HW sin/cos (REVOLUTIONS, arg in [0,0.5) -> no range reduction).
__device__ __forceinline__ float2 twid(float rev, float sg) {
    return make_float2(__builtin_amdgcn_cosf(rev), sg * __builtin_amdgcn_sinf(rev));
}

// ---- Fused radix-4 passes (== two radix-2 stages; preserves bitrev semantics) ----

// DIF fused pair: stage half=2M then half=M. Input natural at pass entry.
template <int M>
__device__ __forceinline__ void dif_f4(float2* d, int N, int tid, int nt, float sg) {
    const float inv2m = 1.0f / (2.0f * (float)M);
    const float inv4m = 1.0f / (4.0f * (float)M);
    for (int q = tid; q < (N >> 2); q += nt) {
        int j = q & (M - 1);
        int i0 = ((q & ~(M - 1)) << 2) + j;
        float2 x0 = d[i0], x1 = d[i0 + M], x2 = d[i0 + 2 * M], x3 = d[i0 + 3 * M];
        float jf = (float)j;
        float2 wB = twid(jf * inv4m, sg);
        float2 wA = twid(jf * inv2m, sg);
        float2 a0 = cadd(x0, x2);
        float2 a2 = cmul(wB, csub(x0, x2));
        float2 a1 = cadd(x1, x3);
        float2 t = cmul(wB, csub(x1, x3));
        float2 a3 = make_float2(-sg * t.y, sg * t.x);  // (i*sg)*t
        d[i0] = cadd(a0, a1);
        d[i0 + M] = cmul(wA, csub(a0, a1));
        d[i0 + 2 * M] = cadd(a2, a3);
        d[i0 + 3 * M] = cmul(wA, csub(a2, a3));
    }
    __syncthreads();
}

// DIT fused pair: stage half=M then half=2M. Input bitrev at pass entry.
template <int M>
__device__ __forceinline__ void dit_f4(float2* d, int N, int tid, int nt, float sg) {
    const float inv2m = 1.0f / (2.0f * (float)M);
    const float inv4m = 1.0f / (4.0f * (float)M);
    for (int q = tid; q < (N >> 2); q += nt) {
        int j = q & (M - 1);
        int i0 = ((q & ~(M - 1)) << 2) + j;
        float2 x0 = d[i0], x1 = d[i0 + M], x2 = d[i0 + 2 * M], x3 = d[i0 + 3 * M];
        float jf = (float)j;
        float2 wA = twid(jf * inv2m, sg);
        float2 wB = twid(jf * inv4m, sg);
        float2 t0 = cmul(wA, x1), t1 = cmul(wA, x3);
        float2 a0 = cadd(x0, t0), a1 = csub(x0, t0);
        float2 a2 = cadd(x2, t1), a3 = csub(x2, t1);
        float2 u = cmul(wB, a2), v = cmul(wB, a3);
        float2 vi = make_float2(-sg * v.y, sg * v.x);  // (i*sg)*v
        d[i0] = cadd(a0, u);
        d[i0 + 2 * M] = csub(a0, u);
        d[i0 + M] = cadd(a1, vi);
        d[i0 + 3 * M] = csub(a1, vi);
    }
    __syncthreads();
}

// Stage 1 (fused): [cauchy at_roots, 2 pts/thread] ++ [transpose u->ut] ++ [skip=u@D].
// __launch_bounds__(256, 8): pin 8 blocks/CU (VGPR cap 64) — round 8 showed the
// fused kernel lives or dies by whole-kernel occupancy.
__global__ __launch_bounds__(256, 8) void stage1_kernel(
    const float* __restrict__ u,
    const float* __restrict__ B_ri, const float* __restrict__ C_ri,
    const float* __restrict__ D,
    const float* __restrict__ Lambda_ri, const float* __restrict__ P_ri,
    const float* __restrict__ step,
    float2* __restrict__ at_g, float* __restrict__ ut, float* __restrict__ skip) {
    __shared__ float4 smem4[264];  // union: cauchy tables [64*3] 3072B / transpose tile 4224B
    const int bid = blockIdx.x;
    const int tid = threadIdx.x;

    if (bid < CAU_BLOCKS) {
        // ---- Cauchy: h = bid>>3; thread handles l = base + p*2048, p=0,1.
        // 3 broadcast ds_read_b128 per n feed 2 points of VALU (2x amortized vs r6,
        // half the VGPR cost of r8's 4-pt version).
        const int h = bid >> 3;
        if (tid < NN) {
            int n = tid;
            float2 C = ((const float2*)C_ri)[h * NN + n];
            float2 Bv = ((const float2*)B_ri)[h * NN + n];
            float2 P = ((const float2*)P_ri)[h * NN + n];
            float2 lam = ((const float2*)Lambda_ri)[h * NN + n];
            float2 Cc = make_float2(C.x, -C.y);
            float2 Pc = make_float2(P.x, -P.y);
            float2 v00 = cmul(Cc, Bv);
            float2 v01 = cmul(Cc, P);
            float2 v10 = cmul(Pc, Bv);
            float2 v11 = cmul(Pc, P);
            smem4[n * 3 + 0] = make_float4(lam.x, lam.y, v00.x, v00.y);
            smem4[n * 3 + 1] = make_float4(v01.x, v01.y, v10.x, v10.y);
            smem4[n * 3 + 2] = make_float4(v11.x, v11.y, 0.f, 0.f);
        }
        __syncthreads();

        const int lbase = ((bid & 7) << 8) | tid;  // [0, 2048)
        const float two_over_step = 2.0f / step[0];
        float gr[2], gi[2], ccx[2], ccy[2];
#pragma unroll
        for (int p = 0; p < 2; ++p) {
            int l = lbase + p * 2048;
            // z = exp(-2*pi*i*l/L). libm sincosf: at l=2048 the fp32-pi inexactness
            // keeps 1+z away from exactly 0 (matches reference behavior). DO NOT
            // replace with HW sin/cos here.
            double th = -6.283185307179586476925286766559 * (double)l / (double)LL;
            float sn, cs;
            sincosf((float)th, &sn, &cs);
            float dr = 1.0f + cs, di = sn;  // 1+z
            float inv = __builtin_amdgcn_rcpf(dr * dr + di * di);
            float nr = 1.0f - cs, ni = -sn;  // 1-z
            gr[p] = two_over_step * (nr * dr + ni * di) * inv;
            gi[p] = two_over_step * (ni * dr - nr * di) * inv;
            ccx[p] = 2.0f * dr * inv;
            ccy[p] = -2.0f * di * inv;
        }

        float2 k00[2], k01[2], k10[2], k11[2];
#pragma unroll
        for (int p = 0; p < 2; ++p) {
            k00[p] = make_float2(0.f, 0.f);
            k01[p] = make_float2(0.f, 0.f);
            k10[p] = make_float2(0.f, 0.f);
            k11[p] = make_float2(0.f, 0.f);
        }
#pragma unroll 4
        for (int n = 0; n < NN; ++n) {
            float4 tA = smem4[n * 3 + 0];
            float4 tB = smem4[n * 3 + 1];
            float4 tC = smem4[n * 3 + 2];
#pragma unroll
            for (int p = 0; p < 2; ++p) {
                float ar = gr[p] - tA.x, ai = gi[p] - tA.y;
                float id = __builtin_amdgcn_rcpf(ar * ar + ai * ai);
                float2 r = make_float2(ar * id, -ai * id);  // 1/(g-lambda)
                k00[p] = cadd(k00[p], cmul(make_float2(tA.z, tA.w), r));
                k01[p] = cadd(k01[p], cmul(make_float2(tB.x, tB.y), r));
                k10[p] = cadd(k10[p], cmul(make_float2(tB.z, tB.w), r));
                k11[p] = cadd(k11[p], cmul(make_float2(tC.x, tC.y), r));
            }
        }
#pragma unroll
        for (int p = 0; p < 2; ++p) {
            float wr = 1.0f + k11[p].x, wi = k11[p].y;
            float iw = __builtin_amdgcn_rcpf(wr * wr + wi * wi);
            float2 winv = make_float2(wr * iw, -wi * iw);
            float2 t = cmul(cmul(k01[p], winv), k10[p]);
            float2 at = cmul(make_float2(ccx[p], ccy[p]),
                             make_float2(k00[p].x - t.x, k00[p].y - t.y));
            at_g[(size_t)h * LL + lbase + p * 2048] = at;
        }
    } else if (bid < CAU_BLOCKS + TRU_BLOCKS) {
        // ---- Transpose: u [B,L,H] -> ut [B,H,L], 32x32 tiles ----
        float* tile = (float*)smem4;  // [32][33]
        int tb = bid - CAU_BLOCKS;
        int b = tb >> 9;
        int h0 = ((tb >> 7) & 3) * 32;
        int l0 = (tb & 127) * 32;
        int tx = tid & 31, ty = tid >> 5;  // ty 0..7
        const float* up = u + (size_t)b * LL * HH;
        float* utp = ut + (size_t)b * HH * LL;
        for (int i = ty; i < 32; i += 8)
            tile[i * 33 + tx] = up[(size_t)(l0 + i) * HH + h0 + tx];
        __syncthreads();
        for (int i = ty; i < 32; i += 8)
            utp[(size_t)(h0 + i) * LL + l0 + tx] = tile[tx * 33 + i];
    } else {
        // ---- Skip: skip[row] = sum_h u[row,h]*D[h]; 1 row per 64-lane wave ----
        int sb = bid - (CAU_BLOCKS + TRU_BLOCKS);  // [0, 8192)
        int wid = tid >> 6, lane = tid & 63;
        int row = sb * 4 + wid;
        const float* ur = u + (size_t)row * HH;
        float v = ur[lane] * D[lane] + ur[lane + 64] * D[lane + 64];
        for (int off = 32; off > 0; off >>= 1) v += __shfl_down(v, off, 64);
        if (lane == 0) skip[row] = v;
    }
}

// Kernel A2: per h — scatter-load at -> IFFT4096 -> fused {scale + pad + head-r2}
// -> FFT8192 (remaining 12 stages) -> store permuted K spectrum KfP[h][t] = K_h(kk(t)).
__global__ __launch_bounds__(1024) void kfreq_kernel(const float2* __restrict__ at_g,
                                                     float2* __restrict__ KfP) {
    __shared__ float2 sm[NFFT];  // 64 KB
    const int h = blockIdx.x;
    const int tid = threadIdx.x;
    const float2* ap = at_g + (size_t)h * LL;
#pragma unroll
    for (int it = 0; it < 4; ++it) {
        int t = tid + it * 1024;
        int l = ((t & 63) << 6) | (t >> 6);     // low6<->high6 swap
        sm[__brev((unsigned)l) >> 20] = ap[l];  // LDS slot low bits vary per lane
    }
    __syncthreads();

    // inverse FFT 4096 (bitrev in -> natural out)
    dit_f4<1>(sm, 4096, tid, 1024, +1.f);
    dit_f4<4>(sm, 4096, tid, 1024, +1.f);
    dit_f4<16>(sm, 4096, tid, 1024, +1.f);
    dit_f4<64>(sm, 4096, tid, 1024, +1.f);
    dit_f4<256>(sm, 4096, tid, 1024, +1.f);
    dit_f4<1024>(sm, 4096, tid, 1024, +1.f);

    // fused: k = real/4096, zero-pad, and head radix-2 DIF stage (upper half = w*k)
    const float inv8192 = 1.0f / 8192.0f;
    for (int t = tid; t < 4096; t += 1024) {
        float kv = sm[t].x * (1.0f / 4096.0f);
        float2 w = twid((float)t * inv8192, -1.f);
        sm[t] = make_float2(kv, 0.f);
        sm[t + 4096] = make_float2(kv * w.x, kv * w.y);
    }
    __syncthreads();

    // forward FFT 8192, remaining stages (natural in -> bitrev13 out)
    dif_f4<1024>(sm, 8192, tid, 1024, -1.f);
    dif_f4<256>(sm, 8192, tid, 1024, -1.f);
    dif_f4<64>(sm, 8192, tid, 1024, -1.f);
    dif_f4<16>(sm, 8192, tid, 1024, -1.f);
    dif_f4<4>(sm, 8192, tid, 1024, -1.f);
    dif_f4<1>(sm, 8192, tid, 1024, -1.f);

    // permuted store: conv reads K linearly in t (coalesced); LDS gather is cheap here
    float2* kfp = KfP + (size_t)h * KSTR;
    for (int t = tid; t <= 4096; t += 1024) kfp[t] = sm[brev13(kkmap(t))];
}

// Kernel C: two-for-one conv — pack (h0,h1) as re+im; fused {load + head-r2};
// fwd FFT (12 remaining stages); pointwise with coalesced permuted K; inv FFT
// (12 stages) with fused {tail-r2 + scale + store}.
__global__ __launch_bounds__(1024) void conv_fft_kernel(const float* __restrict__ ut,
                                                        const float2* __restrict__ KfP,
                                                        float* __restrict__ yt) {
    __shared__ float2 sm[NFFT];  // 64 KB
    const int b = blockIdx.x >> 6;
    const int c = blockIdx.x & 63;
    const int h0 = 2 * c, h1 = 2 * c + 1;
    const int tid = threadIdx.x;
    const float* up0 = ut + ((size_t)b * HH + h0) * LL;
    const float* up1 = ut + ((size_t)b * HH + h1) * LL;
    const float inv8192 = 1.0f / 8192.0f;

    // fused load + head radix-2 DIF stage (upper half of input is zero)
    for (int i = tid; i < 4096; i += 1024) {
        float2 a = make_float2(up0[i], up1[i]);
        float2 w = twid((float)i * inv8192, -1.f);
        sm[i] = a;
        sm[i + 4096] = cmul(w, a);
    }
    __syncthreads();

    dif_f4<1024>(sm, 8192, tid, 1024, -1.f);
    dif_f4<256>(sm, 8192, tid, 1024, -1.f);
    dif_f4<64>(sm, 8192, tid, 1024, -1.f);
    dif_f4<16>(sm, 8192, tid, 1024, -1.f);
    dif_f4<4>(sm, 8192, tid, 1024, -1.f);
    dif_f4<1>(sm, 8192, tid, 1024, -1.f);

    // Pointwise in bitrev order; each thread-iteration owns conjugate pair (k, N-k).
    // K reads are linear in t (coalesced); only K[p] is needed (Hermitian identity).
    const float2* kf0 = KfP + (size_t)h0 * KSTR;
    const float2* kf1 = KfP + (size_t)h1 * KSTR;
    for (int t = tid; t <= 4096; t += 1024) {
        int kk = kkmap(t);
        bool self = (kk == 0) || (kk == 4096);
        int p = brev13(kk);
        int q = self ? p : brev13(NFFT - kk);
        float2 K0 = kf0[t];
        float2 K1 = kf1[t];
        float2 Zp = sm[p];
        float2 Zq = sm[q];
        float2 U0 = make_float2(0.5f * (Zp.x + Zq.x), 0.5f * (Zp.y - Zq.y));
        float2 U1 = make_float2(0.5f * (Zp.y + Zq.y), 0.5f * (Zq.x - Zp.x));
        float2 A = cmul(U0, K0);
        float2 C = cmul(U1, K1);
        sm[p] = make_float2(A.x - C.y, A.y + C.x);             // W[k]   = A + iC
        if (!self) sm[q] = make_float2(A.x + C.y, C.x - A.y);  // W[N-k] = conj(A - iC)
    }
    __syncthreads();

    dit_f4<1>(sm, 8192, tid, 1024, +1.f);
    dit_f4<4>(sm, 8192, tid, 1024, +1.f);
    dit_f4<16>(sm, 8192, tid, 1024, +1.f);
    dit_f4<64>(sm, 8192, tid, 1024, +1.f);
    dit_f4<256>(sm, 8192, tid, 1024, +1.f);
    dit_f4<1024>(sm, 8192, tid, 1024, +1.f);

    // fused tail radix-2 DIT stage + 1/N scale + store (only first 4096 samples kept)
    float* yp0 = yt + ((size_t)b * HH + h0) * LL;
    float* yp1 = yt + ((size_t)b * HH + h1) * LL;
    const float invN = 1.0f / (float)NFFT;
    for (int x = tid; x < 4096; x += 1024) {
        float2 w = twid((float)x * inv8192, +1.f);
        float2 a = sm[x];
        float2 bb = cmul(w, sm[x + 4096]);
        yp0[x] = (a.x + bb.x) * invN;
        yp1[x] = (a.y + bb.y) * invN;
    }
}

// Kernel D: transpose yt [B,H,L] -> y [B,L,H], add broadcast skip[b,l]
__global__ __launch_bounds__(256) void transpose_y_kernel(const float* __restrict__ yt,
                                                          const float* __restrict__ skip,
                                                          float* __restrict__ y) {
    __shared__ float tile[32][33];
    int b = blockIdx.z;
    int h0 = blockIdx.x * 32, l0 = blockIdx.y * 32;
    const float* ytp = yt + (size_t)b * HH * LL;
    const float* skp = skip + (size_t)b * LL;
    float* yp = y + (size_t)b * LL * HH;
    for (int i = threadIdx.y; i < 32; i += 8)
        tile[i][threadIdx.x] = ytp[(size_t)(h0 + i) * LL + l0 + threadIdx.x];
    __syncthreads();
    for (int i = threadIdx.y; i < 32; i += 8) {
        size_t idx = (size_t)(l0 + i) * HH + h0 + threadIdx.x;
        yp[idx] = tile[threadIdx.x][i] + skp[l0 + i];
    }
}

extern "C" void kernel_launch(void* const* d_in, const int* in_sizes, int n_in,
                              void* d_out, int out_size, void* d_ws, size_t ws_size,
                              hipStream_t stream) {
    const float* u = (const float*)d_in[0];
    const float* B_ri = (const float*)d_in[1];
    const float* C_ri = (const float*)d_in[2];
    const float* D = (const float*)d_in[3];
    const float* Lambda_ri = (const float*)d_in[4];
    const float* P_ri = (const float*)d_in[5];
    const float* step = (const float*)d_in[6];
    float* out = (float*)d_out;

    char* ws = (char*)d_ws;
    float2* KfP = (float2*)ws;                             // ~4.2 MB @ 0
    float* skip = (float*)(ws + (size_t)6 * 1024 * 1024);  // 128 KB @ 6 MB
    float* ut = (float*)(ws + (size_t)8 * 1024 * 1024);    // 16 MB @ 8 MB
    float* yt = (float*)(ws + (size_t)24 * 1024 * 1024);   // 16 MB @ 24 MB
    // at_g aliases yt: written by stage1, consumed by kfreq before conv writes yt.
    float2* at_g = (float2*)yt;                            // 4 MB

    stage1_kernel<<<dim3(CAU_BLOCKS + TRU_BLOCKS + SKP_BLOCKS), dim3(256), 0, stream>>>(
        u, B_ri, C_ri, D, Lambda_ri, P_ri, step, at_g, ut, skip);
    kfreq_kernel<<<dim3(HH), dim3(1024), 0, stream>>>(at_g, KfP);
    conv_fft_kernel<<<dim3(BB * HH / 2), dim3(1024), 0, stream>>>(ut, KfP, yt);
    transpose_y_kernel<<<dim3(HH / 32, LL / 32, BB), dim3(32, 8), 0, stream>>>(yt, skip, out);
}

// Round 10
// 83.430 us; speedup vs baseline: 1.2980x; 1.1023x over previous
//
#include <hip/hip_runtime.h>
#include <hip/hip_bf16.h>
#include <math.h>

#define HH 128
#define NN 64
#define LL 4096
#define BB 8
#define NFFT 8192
#define KSTR 4160  // per-h stride of permuted K spectrum (4097 used, padded)

// stage1 grid partitions (round-9 winner, unchanged)
#define CAU_BLOCKS 1024   // 128 h x 8 l-blocks; each thread does 2 l-points
#define TRU_BLOCKS 4096   // 8 b x 4 h-tiles x 128 l-tiles (32x32)
#define SKP_BLOCKS 8192   // 4 rows/block (1 row per 64-lane wave)

__device__ __forceinline__ float2 cmul(float2 a, float2 b) {
    return make_float2(a.x * b.x - a.y * b.y, a.x * b.y + a.y * b.x);
}
__device__ __forceinline__ float2 cadd(float2 a, float2 b) {
    return make_float2(a.x + b.x, a.y + b.y);
}
__device__ __forceinline__ float2 csub(float2 a, float2 b) {
    return make_float2(a.x - b.x, a.y - b.y);
}
__device__ __forceinline__ int brev13(int x) { return (int)(__brev((unsigned)x) >> 19); }
__device__ __forceinline__ int kkmap(int t) {
    return (t < 4096) ? (((t & 63) << 6) | (t >> 6)) : 4096;
}
// LDS bank swizzle: bijective within 16-elem groups, keeps 8B alignment,
// swz(v+4096)==swz(v)+4096. Makes every FFT pass stride conflict-free.
__device__ __forceinline__ int swz(int v) { return v ^ ((v >> 4) & 15); }

// Twiddle via HW sin/cos (REVOLUTIONS, arg in [0,0.5) -> no range reduction).
__device__ __forceinline__ float2 twid(float rev, float sg) {
    return make_float2(__builtin_amdgcn_cosf(rev), sg * __builtin_amdgcn_sinf(rev));
}

// ---- Fused radix-8 passes (== three radix-2 stages; preserve bitrev semantics).
// Derived as verified-r2-head + verified-f4 composition. All LDS indices swizzled.

// DIF fused triple: stages half=4M, 2M, M. Input natural at pass entry.
template <int M>
__device__ __forceinline__ void dif_f8(float2* d, int N, int tid, int nt, float sg) {
    const float inv2m = 1.0f / (2.0f * (float)M);
    const float inv4m = 1.0f / (4.0f * (float)M);
    const float inv8m = 1.0f / (8.0f * (float)M);
    const float s2 = 0.70710678118654752f;
    for (int q = tid; q < (N >> 3); q += nt) {
        int j = q & (M - 1);
        int i0 = ((q & ~(M - 1)) << 3) + j;
        float2 x0 = d[swz(i0)],         x1 = d[swz(i0 + M)],
               x2 = d[swz(i0 + 2 * M)], x3 = d[swz(i0 + 3 * M)],
               x4 = d[swz(i0 + 4 * M)], x5 = d[swz(i0 + 5 * M)],
               x6 = d[swz(i0 + 6 * M)], x7 = d[swz(i0 + 7 * M)];
        float jf = (float)j;
        float2 w8 = twid(jf * inv8m, sg);
        float2 w4 = twid(jf * inv4m, sg);
        float2 w2 = twid(jf * inv2m, sg);
        float2 e1 = make_float2(s2, sg * s2);
        float2 e3 = make_float2(-s2, sg * s2);
        // stage half=4M: y=lower, z=w8*e8^k*(upper diff)
        float2 y0 = cadd(x0, x4), y1 = cadd(x1, x5), y2 = cadd(x2, x6), y3 = cadd(x3, x7);
        float2 t0 = csub(x0, x4), t1 = csub(x1, x5), t2 = csub(x2, x6), t3 = csub(x3, x7);
        float2 w8i = make_float2(-sg * w8.y, sg * w8.x);  // w8 * (i*sg)
        float2 z0 = cmul(w8, t0);
        float2 z1 = cmul(cmul(w8, e1), t1);
        float2 z2 = cmul(w8i, t2);
        float2 z3 = cmul(cmul(w8, e3), t3);
        {   // dif_f4 on y at offsets 0..3M
            float2 a0 = cadd(y0, y2);
            float2 a2 = cmul(w4, csub(y0, y2));
            float2 a1 = cadd(y1, y3);
            float2 t = cmul(w4, csub(y1, y3));
            float2 a3 = make_float2(-sg * t.y, sg * t.x);
            d[swz(i0)]         = cadd(a0, a1);
            d[swz(i0 + M)]     = cmul(w2, csub(a0, a1));
            d[swz(i0 + 2 * M)] = cadd(a2, a3);
            d[swz(i0 + 3 * M)] = cmul(w2, csub(a2, a3));
        }
        {   // dif_f4 on z at offsets 4M..7M
            float2 a0 = cadd(z0, z2);
            float2 a2 = cmul(w4, csub(z0, z2));
            float2 a1 = cadd(z1, z3);
            float2 t = cmul(w4, csub(z1, z3));
            float2 a3 = make_float2(-sg * t.y, sg * t.x);
            d[swz(i0 + 4 * M)] = cadd(a0, a1);
            d[swz(i0 + 5 * M)] = cmul(w2, csub(a0, a1));
            d[swz(i0 + 6 * M)] = cadd(a2, a3);
            d[swz(i0 + 7 * M)] = cmul(w2, csub(a2, a3));
        }
    }
    __syncthreads();
}

// DIT fused triple: stages half=M, 2M, 4M. Input bitrev at pass entry.
template <int M>
__device__ __forceinline__ void dit_f8(float2* d, int N, int tid, int nt, float sg) {
    const float inv2m = 1.0f / (2.0f * (float)M);
    const float inv4m = 1.0f / (4.0f * (float)M);
    const float inv8m = 1.0f / (8.0f * (float)M);
    const float s2 = 0.70710678118654752f;
    for (int q = tid; q < (N >> 3); q += nt) {
        int j = q & (M - 1);
        int i0 = ((q & ~(M - 1)) << 3) + j;
        float2 x0 = d[swz(i0)],         x1 = d[swz(i0 + M)],
               x2 = d[swz(i0 + 2 * M)], x3 = d[swz(i0 + 3 * M)],
               x4 = d[swz(i0 + 4 * M)], x5 = d[swz(i0 + 5 * M)],
               x6 = d[swz(i0 + 6 * M)], x7 = d[swz(i0 + 7 * M)];
        float jf = (float)j;
        float2 wA = twid(jf * inv2m, sg);
        float2 wB = twid(jf * inv4m, sg);
        float2 wC = twid(jf * inv8m, sg);
        float2 t;
        // stage half=M
        t = cmul(wA, x1); float2 b0 = cadd(x0, t), b1 = csub(x0, t);
        t = cmul(wA, x3); float2 b2 = cadd(x2, t), b3 = csub(x2, t);
        t = cmul(wA, x5); float2 b4 = cadd(x4, t), b5 = csub(x4, t);
        t = cmul(wA, x7); float2 b6 = cadd(x6, t), b7 = csub(x6, t);
        // stage half=2M
        float2 wBi = make_float2(-sg * wB.y, sg * wB.x);
        t = cmul(wB, b2);  float2 c0 = cadd(b0, t), c2 = csub(b0, t);
        t = cmul(wBi, b3); float2 c1 = cadd(b1, t), c3 = csub(b1, t);
        t = cmul(wB, b6);  float2 c4 = cadd(b4, t), c6 = csub(b4, t);
        t = cmul(wBi, b7); float2 c5 = cadd(b5, t), c7 = csub(b5, t);
        // stage half=4M, twiddles wC*e8^k
        float2 e1 = make_float2(s2, sg * s2);
        float2 e3 = make_float2(-s2, sg * s2);
        float2 w1 = cmul(wC, e1);
        float2 w2_ = make_float2(-sg * wC.y, sg * wC.x);
        float2 w3 = cmul(wC, e3);
        t = cmul(wC, c4);  d[swz(i0)]         = cadd(c0, t); d[swz(i0 + 4 * M)] = csub(c0, t);
        t = cmul(w1, c5);  d[swz(i0 + M)]     = cadd(c1, t); d[swz(i0 + 5 * M)] = csub(c1, t);
        t = cmul(w2_, c6); d[swz(i0 + 2 * M)] = cadd(c2, t); d[swz(i0 + 6 * M)] = csub(c2, t);
        t = cmul(w3, c7);  d[swz(i0 + 3 * M)] = cadd(c3, t); d[swz(i0 + 7 * M)] = csub(c3, t);
    }
    __syncthreads();
}

// Stage 1 (round-9 winner, unchanged): cauchy 2pt/thread ++ transpose ++ skip.
__global__ __launch_bounds__(256, 8) void stage1_kernel(
    const float* __restrict__ u,
    const float* __restrict__ B_ri, const float* __restrict__ C_ri,
    const float* __restrict__ D,
    const float* __restrict__ Lambda_ri, const float* __restrict__ P_ri,
    const float* __restrict__ step,
    float2* __restrict__ at_g, float* __restrict__ ut, float* __restrict__ skip) {
    __shared__ float4 smem4[264];
    const int bid = blockIdx.x;
    const int tid = threadIdx.x;

    if (bid < CAU_BLOCKS) {
        const int h = bid >> 3;
        if (tid < NN) {
            int n = tid;
            float2 C = ((const float2*)C_ri)[h * NN + n];
            float2 Bv = ((const float2*)B_ri)[h * NN + n];
            float2 P = ((const float2*)P_ri)[h * NN + n];
            float2 lam = ((const float2*)Lambda_ri)[h * NN + n];
            float2 Cc = make_float2(C.x, -C.y);
            float2 Pc = make_float2(P.x, -P.y);
            float2 v00 = cmul(Cc, Bv);
            float2 v01 = cmul(Cc, P);
            float2 v10 = cmul(Pc, Bv);
            float2 v11 = cmul(Pc, P);
            smem4[n * 3 + 0] = make_float4(lam.x, lam.y, v00.x, v00.y);
            smem4[n * 3 + 1] = make_float4(v01.x, v01.y, v10.x, v10.y);
            smem4[n * 3 + 2] = make_float4(v11.x, v11.y, 0.f, 0.f);
        }
        __syncthreads();

        const int lbase = ((bid & 7) << 8) | tid;  // [0, 2048)
        const float two_over_step = 2.0f / step[0];
        float gr[2], gi[2], ccx[2], ccy[2];
#pragma unroll
        for (int p = 0; p < 2; ++p) {
            int l = lbase + p * 2048;
            // libm sincosf: at l=2048 the fp32-pi inexactness keeps 1+z away from
            // exactly 0 (matches reference). DO NOT replace with HW sin/cos.
            double th = -6.283185307179586476925286766559 * (double)l / (double)LL;
            float sn, cs;
            sincosf((float)th, &sn, &cs);
            float dr = 1.0f + cs, di = sn;
            float inv = __builtin_amdgcn_rcpf(dr * dr + di * di);
            float nr = 1.0f - cs, ni = -sn;
            gr[p] = two_over_step * (nr * dr + ni * di) * inv;
            gi[p] = two_over_step * (ni * dr - nr * di) * inv;
            ccx[p] = 2.0f * dr * inv;
            ccy[p] = -2.0f * di * inv;
        }

        float2 k00[2], k01[2], k10[2], k11[2];
#pragma unroll
        for (int p = 0; p < 2; ++p) {
            k00[p] = make_float2(0.f, 0.f);
            k01[p] = make_float2(0.f, 0.f);
            k10[p] = make_float2(0.f, 0.f);
            k11[p] = make_float2(0.f, 0.f);
        }
#pragma unroll 4
        for (int n = 0; n < NN; ++n) {
            float4 tA = smem4[n * 3 + 0];
            float4 tB = smem4[n * 3 + 1];
            float4 tC = smem4[n * 3 + 2];
#pragma unroll
            for (int p = 0; p < 2; ++p) {
                float ar = gr[p] - tA.x, ai = gi[p] - tA.y;
                float id = __builtin_amdgcn_rcpf(ar * ar + ai * ai);
                float2 r = make_float2(ar * id, -ai * id);
                k00[p] = cadd(k00[p], cmul(make_float2(tA.z, tA.w), r));
                k01[p] = cadd(k01[p], cmul(make_float2(tB.x, tB.y), r));
                k10[p] = cadd(k10[p], cmul(make_float2(tB.z, tB.w), r));
                k11[p] = cadd(k11[p], cmul(make_float2(tC.x, tC.y), r));
            }
        }
#pragma unroll
        for (int p = 0; p < 2; ++p) {
            float wr = 1.0f + k11[p].x, wi = k11[p].y;
            float iw = __builtin_amdgcn_rcpf(wr * wr + wi * wi);
            float2 winv = make_float2(wr * iw, -wi * iw);
            float2 t = cmul(cmul(k01[p], winv), k10[p]);
            float2 at = cmul(make_float2(ccx[p], ccy[p]),
                             make_float2(k00[p].x - t.x, k00[p].y - t.y));
            at_g[(size_t)h * LL + lbase + p * 2048] = at;
        }
    } else if (bid < CAU_BLOCKS + TRU_BLOCKS) {
        float* tile = (float*)smem4;  // [32][33]
        int tb = bid - CAU_BLOCKS;
        int b = tb >> 9;
        int h0 = ((tb >> 7) & 3) * 32;
        int l0 = (tb & 127) * 32;
        int tx = tid & 31, ty = tid >> 5;
        const float* up = u + (size_t)b * LL * HH;
        float* utp = ut + (size_t)b * HH * LL;
        for (int i = ty; i < 32; i += 8)
            tile[i * 33 + tx] = up[(size_t)(l0 + i) * HH + h0 + tx];
        __syncthreads();
        for (int i = ty; i < 32; i += 8)
            utp[(size_t)(h0 + i) * LL + l0 + tx] = tile[tx * 33 + i];
    } else {
        int sb = bid - (CAU_BLOCKS + TRU_BLOCKS);
        int wid = tid >> 6, lane = tid & 63;
        int row = sb * 4 + wid;
        const float* ur = u + (size_t)row * HH;
        float v = ur[lane] * D[lane] + ur[lane + 64] * D[lane + 64];
        for (int off = 32; off > 0; off >>= 1) v += __shfl_down(v, off, 64);
        if (lane == 0) skip[row] = v;
    }
}

// Kernel A2: per h — scatter-load at -> IFFT4096 (dit_f8 x4) -> fused
// {scale+pad+head-r2} -> FFT8192 (dif_f8 x4) -> permuted K store.
__global__ __launch_bounds__(1024) void kfreq_kernel(const float2* __restrict__ at_g,
                                                     float2* __restrict__ KfP) {
    __shared__ float2 sm[NFFT];  // 64 KB
    const int h = blockIdx.x;
    const int tid = threadIdx.x;
    const float2* ap = at_g + (size_t)h * LL;
#pragma unroll
    for (int it = 0; it < 4; ++it) {
        int t = tid + it * 1024;
        int l = ((t & 63) << 6) | (t >> 6);          // low6<->high6 swap
        sm[swz((int)(__brev((unsigned)l) >> 20))] = ap[l];
    }
    __syncthreads();

    // inverse FFT 4096 (bitrev in -> natural out): 12 stages = dit_f8 x4
    dit_f8<1>(sm, 4096, tid, 1024, +1.f);
    dit_f8<8>(sm, 4096, tid, 1024, +1.f);
    dit_f8<64>(sm, 4096, tid, 1024, +1.f);
    dit_f8<512>(sm, 4096, tid, 1024, +1.f);

    // fused: k = real/4096, zero-pad, head radix-2 DIF stage (upper half = w*k)
    const float inv8192 = 1.0f / 8192.0f;
    for (int t = tid; t < 4096; t += 1024) {
        float kv = sm[swz(t)].x * (1.0f / 4096.0f);
        float2 w = twid((float)t * inv8192, -1.f);
        sm[swz(t)] = make_float2(kv, 0.f);
        sm[swz(t + 4096)] = make_float2(kv * w.x, kv * w.y);
    }
    __syncthreads();

    // forward FFT 8192, remaining 12 stages = dif_f8 x4 (natural -> bitrev13)
    dif_f8<512>(sm, 8192, tid, 1024, -1.f);
    dif_f8<64>(sm, 8192, tid, 1024, -1.f);
    dif_f8<8>(sm, 8192, tid, 1024, -1.f);
    dif_f8<1>(sm, 8192, tid, 1024, -1.f);

    // permuted store: conv reads K linearly in t (coalesced)
    float2* kfp = KfP + (size_t)h * KSTR;
    for (int t = tid; t <= 4096; t += 1024) kfp[t] = sm[swz(brev13(kkmap(t)))];
}

// Kernel C: two-for-one conv, radix-8 passes + swizzled LDS.
__global__ __launch_bounds__(1024) void conv_fft_kernel(const float* __restrict__ ut,
                                                        const float2* __restrict__ KfP,
                                                        float* __restrict__ yt) {
    __shared__ float2 sm[NFFT];  // 64 KB
    const int b = blockIdx.x >> 6;
    const int c = blockIdx.x & 63;
    const int h0 = 2 * c, h1 = 2 * c + 1;
    const int tid = threadIdx.x;
    const float* up0 = ut + ((size_t)b * HH + h0) * LL;
    const float* up1 = ut + ((size_t)b * HH + h1) * LL;
    const float inv8192 = 1.0f / 8192.0f;

    // fused load + head radix-2 DIF stage (upper half of input is zero)
    for (int i = tid; i < 4096; i += 1024) {
        float2 a = make_float2(up0[i], up1[i]);
        float2 w = twid((float)i * inv8192, -1.f);
        sm[swz(i)] = a;
        sm[swz(i + 4096)] = cmul(w, a);
    }
    __syncthreads();

    dif_f8<512>(sm, 8192, tid, 1024, -1.f);
    dif_f8<64>(sm, 8192, tid, 1024, -1.f);
    dif_f8<8>(sm, 8192, tid, 1024, -1.f);
    dif_f8<1>(sm, 8192, tid, 1024, -1.f);

    // Pointwise in bitrev order; each thread-iteration owns conjugate pair (k, N-k).
    const float2* kf0 = KfP + (size_t)h0 * KSTR;
    const float2* kf1 = KfP + (size_t)h1 * KSTR;
    for (int t = tid; t <= 4096; t += 1024) {
        int kk = kkmap(t);
        bool self = (kk == 0) || (kk == 4096);
        int p = swz(brev13(kk));
        int q = self ? p : swz(brev13(NFFT - kk));
        float2 K0 = kf0[t];
        float2 K1 = kf1[t];
        float2 Zp = sm[p];
        float2 Zq = sm[q];
        float2 U0 = make_float2(0.5f * (Zp.x + Zq.x), 0.5f * (Zp.y - Zq.y));
        float2 U1 = make_float2(0.5f * (Zp.y + Zq.y), 0.5f * (Zq.x - Zp.x));
        float2 A = cmul(U0, K0);
        float2 C = cmul(U1, K1);
        sm[p] = make_float2(A.x - C.y, A.y + C.x);             // W[k]   = A + iC
        if (!self) sm[q] = make_float2(A.x + C.y, C.x - A.y);  // W[N-k] = conj(A - iC)
    }
    __syncthreads();

    dit_f8<1>(sm, 8192, tid, 1024, +1.f);
    dit_f8<8>(sm, 8192, tid, 1024, +1.f);
    dit_f8<64>(sm, 8192, tid, 1024, +1.f);
    dit_f8<512>(sm, 8192, tid, 1024, +1.f);

    // fused tail radix-2 DIT stage (half=4096) + 1/N scale + store first 4096
    float* yp0 = yt + ((size_t)b * HH + h0) * LL;
    float* yp1 = yt + ((size_t)b * HH + h1) * LL;
    const float invN = 1.0f / (float)NFFT;
    for (int x = tid; x < 4096; x += 1024) {
        float2 w = twid((float)x * inv8192, +1.f);
        float2 a = sm[swz(x)];
        float2 bb = cmul(w, sm[swz(x + 4096)]);
        yp0[x] = (a.x + bb.x) * invN;
        yp1[x] = (a.y + bb.y) * invN;
    }
}

// Kernel D: transpose yt [B,H,L] -> y [B,L,H], add broadcast skip[b,l]
__global__ __launch_bounds__(256) void transpose_y_kernel(const float* __restrict__ yt,
                                                          const float* __restrict__ skip,
                                                          float* __restrict__ y) {
    __shared__ float tile[32][33];
    int b = blockIdx.z;
    int h0 = blockIdx.x * 32, l0 = blockIdx.y * 32;
    const float* ytp = yt + (size_t)b * HH * LL;
    const float* skp = skip + (size_t)b * LL;
    float* yp = y + (size_t)b * LL * HH;
    for (int i = threadIdx.y; i < 32; i += 8)
        tile[i][threadIdx.x] = ytp[(size_t)(h0 + i) * LL + l0 + threadIdx.x];
    __syncthreads();
    for (int i = threadIdx.y; i < 32; i += 8) {
        size_t idx = (size_t)(l0 + i) * HH + h0 + threadIdx.x;
        yp[idx] = tile[threadIdx.x][i] + skp[l0 + i];
    }
}

extern "C" void kernel_launch(void* const* d_in, const int* in_sizes, int n_in,
                              void* d_out, int out_size, void* d_ws, size_t ws_size,
                              hipStream_t stream) {
    const float* u = (const float*)d_in[0];
    const float* B_ri = (const float*)d_in[1];
    const float* C_ri = (const float*)d_in[2];
    const float* D = (const float*)d_in[3];
    const float* Lambda_ri = (const float*)d_in[4];
    const float* P_ri = (const float*)d_in[5];
    const float* step = (const float*)d_in[6];
    float* out = (float*)d_out;

    char* ws = (char*)d_ws;
    float2* KfP = (float2*)ws;                             // ~4.2 MB @ 0
    float* skip = (float*)(ws + (size_t)6 * 1024 * 1024);  // 128 KB @ 6 MB
    float* ut = (float*)(ws + (size_t)8 * 1024 * 1024);    // 16 MB @ 8 MB
    float* yt = (float*)(ws + (size_t)24 * 1024 * 1024);   // 16 MB @ 24 MB
    // at_g aliases yt: written by stage1, consumed by kfreq before conv writes yt.
    float2* at_g = (float2*)yt;                            // 4 MB

    stage1_kernel<<<dim3(CAU_BLOCKS + TRU_BLOCKS + SKP_BLOCKS), dim3(256), 0, stream>>>(
        u, B_ri, C_ri, D, Lambda_ri, P_ri, step, at_g, ut, skip);
    kfreq_kernel<<<dim3(HH), dim3(1024), 0, stream>>>(at_g, KfP);
    conv_fft_kernel<<<dim3(BB * HH / 2), dim3(1024), 0, stream>>>(ut, KfP, yt);
    transpose_y_kernel<<<dim3(HH / 32, LL / 32, BB), dim3(32, 8), 0, stream>>>(yt, skip, out);
}

// Round 11
// 82.582 us; speedup vs baseline: 1.3114x; 1.0103x over previous
//
#include <hip/hip_runtime.h>
#include <hip/hip_bf16.h>
#include <hip/hip_fp16.h>
#include <math.h>

#define HH 128
#define NN 64
#define LL 4096
#define BB 8
#define NFFT 8192
#define KSTR 4160  // per-h stride of permuted K spectrum (4097 used, padded)

// stage1 grid partitions (skip partition folded into transpose tiles)
#define CAU_BLOCKS 1024   // 128 h x 8 l-blocks; each thread does 2 l-points
#define TRU_BLOCKS 4096   // 8 b x 4 h-tiles x 128 l-tiles (32x32)

__device__ __forceinline__ float2 cmul(float2 a, float2 b) {
    return make_float2(a.x * b.x - a.y * b.y, a.x * b.y + a.y * b.x);
}
__device__ __forceinline__ float2 cadd(float2 a, float2 b) {
    return make_float2(a.x + b.x, a.y + b.y);
}
__device__ __forceinline__ float2 csub(float2 a, float2 b) {
    return make_float2(a.x - b.x, a.y - b.y);
}
__device__ __forceinline__ int brev13(int x) { return (int)(__brev((unsigned)x) >> 19); }
__device__ __forceinline__ int kkmap(int t) {
    return (t < 4096) ? (((t & 63) << 6) | (t >> 6)) : 4096;
}
// LDS bank swizzle: bijective within 16-elem groups, keeps 8B alignment,
// swz(v+4096)==swz(v)+4096. Makes every FFT pass stride conflict-free.
__device__ __forceinline__ int swz(int v) { return v ^ ((v >> 4) & 15); }

// Twiddle via HW sin/cos (REVOLUTIONS, arg in [0,0.5) -> no range reduction).
__device__ __forceinline__ float2 twid(float rev, float sg) {
    return make_float2(__builtin_amdgcn_cosf(rev), sg * __builtin_amdgcn_sinf(rev));
}

// ---- Fused radix-8 passes (three radix-2 stages; bitrev semantics preserved) ----

template <int M>
__device__ __forceinline__ void dif_f8(float2* d, int N, int tid, int nt, float sg) {
    const float inv2m = 1.0f / (2.0f * (float)M);
    const float inv4m = 1.0f / (4.0f * (float)M);
    const float inv8m = 1.0f / (8.0f * (float)M);
    const float s2 = 0.70710678118654752f;
    for (int q = tid; q < (N >> 3); q += nt) {
        int j = q & (M - 1);
        int i0 = ((q & ~(M - 1)) << 3) + j;
        float2 x0 = d[swz(i0)],         x1 = d[swz(i0 + M)],
               x2 = d[swz(i0 + 2 * M)], x3 = d[swz(i0 + 3 * M)],
               x4 = d[swz(i0 + 4 * M)], x5 = d[swz(i0 + 5 * M)],
               x6 = d[swz(i0 + 6 * M)], x7 = d[swz(i0 + 7 * M)];
        float jf = (float)j;
        float2 w8 = twid(jf * inv8m, sg);
        float2 w4 = twid(jf * inv4m, sg);
        float2 w2 = twid(jf * inv2m, sg);
        float2 e1 = make_float2(s2, sg * s2);
        float2 e3 = make_float2(-s2, sg * s2);
        float2 y0 = cadd(x0, x4), y1 = cadd(x1, x5), y2 = cadd(x2, x6), y3 = cadd(x3, x7);
        float2 t0 = csub(x0, x4), t1 = csub(x1, x5), t2 = csub(x2, x6), t3 = csub(x3, x7);
        float2 w8i = make_float2(-sg * w8.y, sg * w8.x);
        float2 z0 = cmul(w8, t0);
        float2 z1 = cmul(cmul(w8, e1), t1);
        float2 z2 = cmul(w8i, t2);
        float2 z3 = cmul(cmul(w8, e3), t3);
        {
            float2 a0 = cadd(y0, y2);
            float2 a2 = cmul(w4, csub(y0, y2));
            float2 a1 = cadd(y1, y3);
            float2 t = cmul(w4, csub(y1, y3));
            float2 a3 = make_float2(-sg * t.y, sg * t.x);
            d[swz(i0)]         = cadd(a0, a1);
            d[swz(i0 + M)]     = cmul(w2, csub(a0, a1));
            d[swz(i0 + 2 * M)] = cadd(a2, a3);
            d[swz(i0 + 3 * M)] = cmul(w2, csub(a2, a3));
        }
        {
            float2 a0 = cadd(z0, z2);
            float2 a2 = cmul(w4, csub(z0, z2));
            float2 a1 = cadd(z1, z3);
            float2 t = cmul(w4, csub(z1, z3));
            float2 a3 = make_float2(-sg * t.y, sg * t.x);
            d[swz(i0 + 4 * M)] = cadd(a0, a1);
            d[swz(i0 + 5 * M)] = cmul(w2, csub(a0, a1));
            d[swz(i0 + 6 * M)] = cadd(a2, a3);
            d[swz(i0 + 7 * M)] = cmul(w2, csub(a2, a3));
        }
    }
    __syncthreads();
}

template <int M>
__device__ __forceinline__ void dit_f8(float2* d, int N, int tid, int nt, float sg) {
    const float inv2m = 1.0f / (2.0f * (float)M);
    const float inv4m = 1.0f / (4.0f * (float)M);
    const float inv8m = 1.0f / (8.0f * (float)M);
    const float s2 = 0.70710678118654752f;
    for (int q = tid; q < (N >> 3); q += nt) {
        int j = q & (M - 1);
        int i0 = ((q & ~(M - 1)) << 3) + j;
        float2 x0 = d[swz(i0)],         x1 = d[swz(i0 + M)],
               x2 = d[swz(i0 + 2 * M)], x3 = d[swz(i0 + 3 * M)],
               x4 = d[swz(i0 + 4 * M)], x5 = d[swz(i0 + 5 * M)],
               x6 = d[swz(i0 + 6 * M)], x7 = d[swz(i0 + 7 * M)];
        float jf = (float)j;
        float2 wA = twid(jf * inv2m, sg);
        float2 wB = twid(jf * inv4m, sg);
        float2 wC = twid(jf * inv8m, sg);
        float2 t;
        t = cmul(wA, x1); float2 b0 = cadd(x0, t), b1 = csub(x0, t);
        t = cmul(wA, x3); float2 b2 = cadd(x2, t), b3 = csub(x2, t);
        t = cmul(wA, x5); float2 b4 = cadd(x4, t), b5 = csub(x4, t);
        t = cmul(wA, x7); float2 b6 = cadd(x6, t), b7 = csub(x6, t);
        float2 wBi = make_float2(-sg * wB.y, sg * wB.x);
        t = cmul(wB, b2);  float2 c0 = cadd(b0, t), c2 = csub(b0, t);
        t = cmul(wBi, b3); float2 c1 = cadd(b1, t), c3 = csub(b1, t);
        t = cmul(wB, b6);  float2 c4 = cadd(b4, t), c6 = csub(b4, t);
        t = cmul(wBi, b7); float2 c5 = cadd(b5, t), c7 = csub(b5, t);
        float2 e1 = make_float2(s2, sg * s2);
        float2 e3 = make_float2(-s2, sg * s2);
        float2 w1 = cmul(wC, e1);
        float2 w2_ = make_float2(-sg * wC.y, sg * wC.x);
        float2 w3 = cmul(wC, e3);
        t = cmul(wC, c4);  d[swz(i0)]         = cadd(c0, t); d[swz(i0 + 4 * M)] = csub(c0, t);
        t = cmul(w1, c5);  d[swz(i0 + M)]     = cadd(c1, t); d[swz(i0 + 5 * M)] = csub(c1, t);
        t = cmul(w2_, c6); d[swz(i0 + 2 * M)] = cadd(c2, t); d[swz(i0 + 6 * M)] = csub(c2, t);
        t = cmul(w3, c7);  d[swz(i0 + 3 * M)] = cadd(c3, t); d[swz(i0 + 7 * M)] = csub(c3, t);
    }
    __syncthreads();
}

// Stage 1: [cauchy 2pt/thread] ++ [transpose u->ut2 (packed h-pairs) + skip partials].
__global__ __launch_bounds__(256, 8) void stage1_kernel(
    const float* __restrict__ u,
    const float* __restrict__ B_ri, const float* __restrict__ C_ri,
    const float* __restrict__ D,
    const float* __restrict__ Lambda_ri, const float* __restrict__ P_ri,
    const float* __restrict__ step,
    float2* __restrict__ at_g, float2* __restrict__ ut2, float* __restrict__ skipP) {
    __shared__ float4 smem4[264];  // union: cauchy tables 3072B / transpose tile 4224B
    const int bid = blockIdx.x;
    const int tid = threadIdx.x;

    if (bid < CAU_BLOCKS) {
        const int h = bid >> 3;
        if (tid < NN) {
            int n = tid;
            float2 C = ((const float2*)C_ri)[h * NN + n];
            float2 Bv = ((const float2*)B_ri)[h * NN + n];
            float2 P = ((const float2*)P_ri)[h * NN + n];
            float2 lam = ((const float2*)Lambda_ri)[h * NN + n];
            float2 Cc = make_float2(C.x, -C.y);
            float2 Pc = make_float2(P.x, -P.y);
            float2 v00 = cmul(Cc, Bv);
            float2 v01 = cmul(Cc, P);
            float2 v10 = cmul(Pc, Bv);
            float2 v11 = cmul(Pc, P);
            smem4[n * 3 + 0] = make_float4(lam.x, lam.y, v00.x, v00.y);
            smem4[n * 3 + 1] = make_float4(v01.x, v01.y, v10.x, v10.y);
            smem4[n * 3 + 2] = make_float4(v11.x, v11.y, 0.f, 0.f);
        }
        __syncthreads();

        const int lbase = ((bid & 7) << 8) | tid;  // [0, 2048)
        const float two_over_step = 2.0f / step[0];
        float gr[2], gi[2], ccx[2], ccy[2];
#pragma unroll
        for (int p = 0; p < 2; ++p) {
            int l = lbase + p * 2048;
            // libm sincosf: at l=2048 the fp32-pi inexactness keeps 1+z away from
            // exactly 0 (matches reference). DO NOT replace with HW sin/cos.
            double th = -6.283185307179586476925286766559 * (double)l / (double)LL;
            float sn, cs;
            sincosf((float)th, &sn, &cs);
            float dr = 1.0f + cs, di = sn;
            float inv = __builtin_amdgcn_rcpf(dr * dr + di * di);
            float nr = 1.0f - cs, ni = -sn;
            gr[p] = two_over_step * (nr * dr + ni * di) * inv;
            gi[p] = two_over_step * (ni * dr - nr * di) * inv;
            ccx[p] = 2.0f * dr * inv;
            ccy[p] = -2.0f * di * inv;
        }

        float2 k00[2], k01[2], k10[2], k11[2];
#pragma unroll
        for (int p = 0; p < 2; ++p) {
            k00[p] = make_float2(0.f, 0.f);
            k01[p] = make_float2(0.f, 0.f);
            k10[p] = make_float2(0.f, 0.f);
            k11[p] = make_float2(0.f, 0.f);
        }
#pragma unroll 4
        for (int n = 0; n < NN; ++n) {
            float4 tA = smem4[n * 3 + 0];
            float4 tB = smem4[n * 3 + 1];
            float4 tC = smem4[n * 3 + 2];
#pragma unroll
            for (int p = 0; p < 2; ++p) {
                float ar = gr[p] - tA.x, ai = gi[p] - tA.y;
                float id = __builtin_amdgcn_rcpf(ar * ar + ai * ai);
                float2 r = make_float2(ar * id, -ai * id);
                k00[p] = cadd(k00[p], cmul(make_float2(tA.z, tA.w), r));
                k01[p] = cadd(k01[p], cmul(make_float2(tB.x, tB.y), r));
                k10[p] = cadd(k10[p], cmul(make_float2(tB.z, tB.w), r));
                k11[p] = cadd(k11[p], cmul(make_float2(tC.x, tC.y), r));
            }
        }
#pragma unroll
        for (int p = 0; p < 2; ++p) {
            float wr = 1.0f + k11[p].x, wi = k11[p].y;
            float iw = __builtin_amdgcn_rcpf(wr * wr + wi * wi);
            float2 winv = make_float2(wr * iw, -wi * iw);
            float2 t = cmul(cmul(k01[p], winv), k10[p]);
            float2 at = cmul(make_float2(ccx[p], ccy[p]),
                             make_float2(k00[p].x - t.x, k00[p].y - t.y));
            at_g[(size_t)h * LL + lbase + p * 2048] = at;
        }
    } else {
        // ---- Transpose + skip-partials: u [B,L,H] -> ut2 [B,64,L] (float2 h-pairs);
        // skipP[b][hq][l] = sum over this tile's 32 h of u*D.
        float* tile = (float*)smem4;  // [32][33]
        int tb = bid - CAU_BLOCKS;
        int b = tb >> 9;
        int hq = (tb >> 7) & 3;
        int h0 = hq * 32;
        int l0 = (tb & 127) * 32;
        int tx = tid & 31, ty = tid >> 5;  // ty 0..7
        const float* up = u + (size_t)b * LL * HH;
        for (int i = ty; i < 32; i += 8)
            tile[i * 33 + tx] = up[(size_t)(l0 + i) * HH + h0 + tx];
        __syncthreads();
        // packed float2 write: 16 c-pairs x 32 l
        float2* utp = ut2 + (size_t)b * 64 * LL;
#pragma unroll
        for (int i = ty; i < 16; i += 8) {
            int c = (h0 >> 1) + i;
            float2 v = make_float2(tile[tx * 33 + 2 * i], tile[tx * 33 + 2 * i + 1]);
            utp[(size_t)c * LL + l0 + tx] = v;
        }
        // skip partial: thread t -> l_local = t>>3, hgroup g = t&7 (4 h each)
        int llocal = tid >> 3, g = tid & 7;
        float s = 0.f;
#pragma unroll
        for (int k = 0; k < 4; ++k)
            s += tile[llocal * 33 + g * 4 + k] * D[h0 + g * 4 + k];
        s += __shfl_down(s, 4, 8);
        s += __shfl_down(s, 2, 8);
        s += __shfl_down(s, 1, 8);
        if (g == 0) skipP[((size_t)b * 4 + hq) * LL + l0 + llocal] = s;
    }
}

// Kernel A2: per h — scatter-load at -> IFFT4096 (dit_f8 x4) -> fused
// {scale+pad+head-r2} -> FFT8192 (dif_f8 x4) -> permuted K store.
__global__ __launch_bounds__(1024) void kfreq_kernel(const float2* __restrict__ at_g,
                                                     float2* __restrict__ KfP) {
    __shared__ float2 sm[NFFT];  // 64 KB
    const int h = blockIdx.x;
    const int tid = threadIdx.x;
    const float2* ap = at_g + (size_t)h * LL;
#pragma unroll
    for (int it = 0; it < 4; ++it) {
        int t = tid + it * 1024;
        int l = ((t & 63) << 6) | (t >> 6);          // low6<->high6 swap
        sm[swz((int)(__brev((unsigned)l) >> 20))] = ap[l];
    }
    __syncthreads();

    dit_f8<1>(sm, 4096, tid, 1024, +1.f);
    dit_f8<8>(sm, 4096, tid, 1024, +1.f);
    dit_f8<64>(sm, 4096, tid, 1024, +1.f);
    dit_f8<512>(sm, 4096, tid, 1024, +1.f);

    const float inv8192 = 1.0f / 8192.0f;
    for (int t = tid; t < 4096; t += 1024) {
        float kv = sm[swz(t)].x * (1.0f / 4096.0f);
        float2 w = twid((float)t * inv8192, -1.f);
        sm[swz(t)] = make_float2(kv, 0.f);
        sm[swz(t + 4096)] = make_float2(kv * w.x, kv * w.y);
    }
    __syncthreads();

    dif_f8<512>(sm, 8192, tid, 1024, -1.f);
    dif_f8<64>(sm, 8192, tid, 1024, -1.f);
    dif_f8<8>(sm, 8192, tid, 1024, -1.f);
    dif_f8<1>(sm, 8192, tid, 1024, -1.f);

    float2* kfp = KfP + (size_t)h * KSTR;
    for (int t = tid; t <= 4096; t += 1024) kfp[t] = sm[swz(brev13(kkmap(t)))];
}

// Kernel C: two-for-one conv — packed float2 input, half2 output.
__global__ __launch_bounds__(1024) void conv_fft_kernel(const float2* __restrict__ ut2,
                                                        const float2* __restrict__ KfP,
                                                        __half2* __restrict__ yt2) {
    __shared__ float2 sm[NFFT];  // 64 KB
    const int b = blockIdx.x >> 6;
    const int c = blockIdx.x & 63;
    const int h0 = 2 * c, h1 = 2 * c + 1;
    const int tid = threadIdx.x;
    const float2* up2 = ut2 + ((size_t)b * 64 + c) * LL;
    const float inv8192 = 1.0f / 8192.0f;

    // fused load + head radix-2 DIF stage (upper half of input is zero)
    for (int i = tid; i < 4096; i += 1024) {
        float2 a = up2[i];
        float2 w = twid((float)i * inv8192, -1.f);
        sm[swz(i)] = a;
        sm[swz(i + 4096)] = cmul(w, a);
    }
    __syncthreads();

    dif_f8<512>(sm, 8192, tid, 1024, -1.f);
    dif_f8<64>(sm, 8192, tid, 1024, -1.f);
    dif_f8<8>(sm, 8192, tid, 1024, -1.f);
    dif_f8<1>(sm, 8192, tid, 1024, -1.f);

    const float2* kf0 = KfP + (size_t)h0 * KSTR;
    const float2* kf1 = KfP + (size_t)h1 * KSTR;
    for (int t = tid; t <= 4096; t += 1024) {
        int kk = kkmap(t);
        bool self = (kk == 0) || (kk == 4096);
        int p = swz(brev13(kk));
        int q = self ? p : swz(brev13(NFFT - kk));
        float2 K0 = kf0[t];
        float2 K1 = kf1[t];
        float2 Zp = sm[p];
        float2 Zq = sm[q];
        float2 U0 = make_float2(0.5f * (Zp.x + Zq.x), 0.5f * (Zp.y - Zq.y));
        float2 U1 = make_float2(0.5f * (Zp.y + Zq.y), 0.5f * (Zq.x - Zp.x));
        float2 A = cmul(U0, K0);
        float2 C = cmul(U1, K1);
        sm[p] = make_float2(A.x - C.y, A.y + C.x);             // W[k]   = A + iC
        if (!self) sm[q] = make_float2(A.x + C.y, C.x - A.y);  // W[N-k] = conj(A - iC)
    }
    __syncthreads();

    dit_f8<1>(sm, 8192, tid, 1024, +1.f);
    dit_f8<8>(sm, 8192, tid, 1024, +1.f);
    dit_f8<64>(sm, 8192, tid, 1024, +1.f);
    dit_f8<512>(sm, 8192, tid, 1024, +1.f);

    // fused tail radix-2 DIT stage + 1/N scale + packed half2 store
    __half2* yp = yt2 + ((size_t)b * 64 + c) * LL;
    const float invN = 1.0f / (float)NFFT;
    for (int x = tid; x < 4096; x += 1024) {
        float2 w = twid((float)x * inv8192, +1.f);
        float2 a = sm[swz(x)];
        float2 bb = cmul(w, sm[swz(x + 4096)]);
        yp[x] = __floats2half2_rn((a.x + bb.x) * invN, (a.y + bb.y) * invN);
    }
}

// Kernel D: transpose yt2 [B,64,L] (half2) -> y [B,L,H] fp32, add 4-way skip partials.
__global__ __launch_bounds__(256) void transpose_y_kernel(const __half2* __restrict__ yt2,
                                                          const float* __restrict__ skipP,
                                                          float* __restrict__ y) {
    __shared__ __half2 tile[32 * 17];
    int b = blockIdx.z;
    int c0 = blockIdx.x * 16;  // 16 half2 pairs = 32 h
    int l0 = blockIdx.y * 32;
    int tx = threadIdx.x, ty = threadIdx.y;  // 32 x 8
    const __half2* ytp = yt2 + (size_t)b * 64 * LL;
    const float* skp = skipP + (size_t)b * 4 * LL;
    float* yp = y + (size_t)b * LL * HH;
    for (int i = ty; i < 16; i += 8)
        tile[tx * 17 + i] = ytp[(size_t)(c0 + i) * LL + l0 + tx];
    __syncthreads();
    int h0 = c0 * 2;
    for (int i = ty; i < 32; i += 8) {
        int l = l0 + i;
        float sk = skp[l] + skp[LL + l] + skp[2 * LL + l] + skp[3 * LL + l];
        float2 f = __half22float2(tile[i * 17 + (tx >> 1)]);
        float v = (tx & 1) ? f.y : f.x;
        yp[(size_t)l * HH + h0 + tx] = v + sk;
    }
}

extern "C" void kernel_launch(void* const* d_in, const int* in_sizes, int n_in,
                              void* d_out, int out_size, void* d_ws, size_t ws_size,
                              hipStream_t stream) {
    const float* u = (const float*)d_in[0];
    const float* B_ri = (const float*)d_in[1];
    const float* C_ri = (const float*)d_in[2];
    const float* D = (const float*)d_in[3];
    const float* Lambda_ri = (const float*)d_in[4];
    const float* P_ri = (const float*)d_in[5];
    const float* step = (const float*)d_in[6];
    float* out = (float*)d_out;

    char* ws = (char*)d_ws;
    float2* KfP = (float2*)ws;                              // ~4.2 MB @ 0
    float* skipP = (float*)(ws + (size_t)6 * 1024 * 1024);  // 512 KB @ 6 MB
    float2* ut2 = (float2*)(ws + (size_t)8 * 1024 * 1024);  // 16 MB @ 8 MB
    char* hi = ws + (size_t)24 * 1024 * 1024;               // 8 MB region @ 24 MB
    // at_g (4 MB) aliases the yt2 region: written by stage1, consumed by kfreq
    // before conv overwrites it with yt2 (stream-serial).
    float2* at_g = (float2*)hi;
    __half2* yt2 = (__half2*)hi;

    stage1_kernel<<<dim3(CAU_BLOCKS + TRU_BLOCKS), dim3(256), 0, stream>>>(
        u, B_ri, C_ri, D, Lambda_ri, P_ri, step, at_g, ut2, skipP);
    kfreq_kernel<<<dim3(HH), dim3(1024), 0, stream>>>(at_g, KfP);
    conv_fft_kernel<<<dim3(BB * HH / 2), dim3(1024), 0, stream>>>(ut2, KfP, yt2);
    transpose_y_kernel<<<dim3(HH / 32, LL / 32, BB), dim3(32, 8), 0, stream>>>(yt2, skipP, out);
}

// Round 12
// 79.628 us; speedup vs baseline: 1.3600x; 1.0371x over previous
//
#include <hip/hip_runtime.h>
#include <hip/hip_bf16.h>
#include <hip/hip_fp16.h>
#include <math.h>

#define HH 128
#define NN 64
#define LL 4096
#define BB 8
#define NFFT 8192
#define KSTR 4160  // per-h stride of permuted K spectrum (4097 used, padded)

// stage1 grid partitions, dispatch order: cauchy (critical path) -> transpose -> skip
#define CAU_BLOCKS 1024   // 128 h x 8 l-blocks; each thread does 2 l-points
#define TRU_BLOCKS 4096   // 8 b x 4 h-tiles x 128 l-tiles (32x32), packed float2 out
#define SKP_BLOCKS 8192   // 4 rows/block (1 row per 64-lane wave) — backfill

__device__ __forceinline__ float2 cmul(float2 a, float2 b) {
    return make_float2(a.x * b.x - a.y * b.y, a.x * b.y + a.y * b.x);
}
__device__ __forceinline__ float2 cadd(float2 a, float2 b) {
    return make_float2(a.x + b.x, a.y + b.y);
}
__device__ __forceinline__ float2 csub(float2 a, float2 b) {
    return make_float2(a.x - b.x, a.y - b.y);
}
__device__ __forceinline__ int brev13(int x) { return (int)(__brev((unsigned)x) >> 19); }
__device__ __forceinline__ int kkmap(int t) {
    return (t < 4096) ? (((t & 63) << 6) | (t >> 6)) : 4096;
}
// LDS bank swizzle: bijective within 16-elem groups, keeps 8B alignment,
// swz(v+4096)==swz(v)+4096. Makes every FFT pass stride conflict-free.
__device__ __forceinline__ int swz(int v) { return v ^ ((v >> 4) & 15); }

// Twiddle via HW sin/cos (REVOLUTIONS, arg in [0,0.5) -> no range reduction).
__device__ __forceinline__ float2 twid(float rev, float sg) {
    return make_float2(__builtin_amdgcn_cosf(rev), sg * __builtin_amdgcn_sinf(rev));
}

// ---- Fused radix-8 passes (three radix-2 stages; bitrev semantics preserved) ----

template <int M>
__device__ __forceinline__ void dif_f8(float2* d, int N, int tid, int nt, float sg) {
    const float inv2m = 1.0f / (2.0f * (float)M);
    const float inv4m = 1.0f / (4.0f * (float)M);
    const float inv8m = 1.0f / (8.0f * (float)M);
    const float s2 = 0.70710678118654752f;
    for (int q = tid; q < (N >> 3); q += nt) {
        int j = q & (M - 1);
        int i0 = ((q & ~(M - 1)) << 3) + j;
        float2 x0 = d[swz(i0)],         x1 = d[swz(i0 + M)],
               x2 = d[swz(i0 + 2 * M)], x3 = d[swz(i0 + 3 * M)],
               x4 = d[swz(i0 + 4 * M)], x5 = d[swz(i0 + 5 * M)],
               x6 = d[swz(i0 + 6 * M)], x7 = d[swz(i0 + 7 * M)];
        float jf = (float)j;
        float2 w8 = twid(jf * inv8m, sg);
        float2 w4 = twid(jf * inv4m, sg);
        float2 w2 = twid(jf * inv2m, sg);
        float2 e1 = make_float2(s2, sg * s2);
        float2 e3 = make_float2(-s2, sg * s2);
        float2 y0 = cadd(x0, x4), y1 = cadd(x1, x5), y2 = cadd(x2, x6), y3 = cadd(x3, x7);
        float2 t0 = csub(x0, x4), t1 = csub(x1, x5), t2 = csub(x2, x6), t3 = csub(x3, x7);
        float2 w8i = make_float2(-sg * w8.y, sg * w8.x);
        float2 z0 = cmul(w8, t0);
        float2 z1 = cmul(cmul(w8, e1), t1);
        float2 z2 = cmul(w8i, t2);
        float2 z3 = cmul(cmul(w8, e3), t3);
        {
            float2 a0 = cadd(y0, y2);
            float2 a2 = cmul(w4, csub(y0, y2));
            float2 a1 = cadd(y1, y3);
            float2 t = cmul(w4, csub(y1, y3));
            float2 a3 = make_float2(-sg * t.y, sg * t.x);
            d[swz(i0)]         = cadd(a0, a1);
            d[swz(i0 + M)]     = cmul(w2, csub(a0, a1));
            d[swz(i0 + 2 * M)] = cadd(a2, a3);
            d[swz(i0 + 3 * M)] = cmul(w2, csub(a2, a3));
        }
        {
            float2 a0 = cadd(z0, z2);
            float2 a2 = cmul(w4, csub(z0, z2));
            float2 a1 = cadd(z1, z3);
            float2 t = cmul(w4, csub(z1, z3));
            float2 a3 = make_float2(-sg * t.y, sg * t.x);
            d[swz(i0 + 4 * M)] = cadd(a0, a1);
            d[swz(i0 + 5 * M)] = cmul(w2, csub(a0, a1));
            d[swz(i0 + 6 * M)] = cadd(a2, a3);
            d[swz(i0 + 7 * M)] = cmul(w2, csub(a2, a3));
        }
    }
    __syncthreads();
}

template <int M>
__device__ __forceinline__ void dit_f8(float2* d, int N, int tid, int nt, float sg) {
    const float inv2m = 1.0f / (2.0f * (float)M);
    const float inv4m = 1.0f / (4.0f * (float)M);
    const float inv8m = 1.0f / (8.0f * (float)M);
    const float s2 = 0.70710678118654752f;
    for (int q = tid; q < (N >> 3); q += nt) {
        int j = q & (M - 1);
        int i0 = ((q & ~(M - 1)) << 3) + j;
        float2 x0 = d[swz(i0)],         x1 = d[swz(i0 + M)],
               x2 = d[swz(i0 + 2 * M)], x3 = d[swz(i0 + 3 * M)],
               x4 = d[swz(i0 + 4 * M)], x5 = d[swz(i0 + 5 * M)],
               x6 = d[swz(i0 + 6 * M)], x7 = d[swz(i0 + 7 * M)];
        float jf = (float)j;
        float2 wA = twid(jf * inv2m, sg);
        float2 wB = twid(jf * inv4m, sg);
        float2 wC = twid(jf * inv8m, sg);
        float2 t;
        t = cmul(wA, x1); float2 b0 = cadd(x0, t), b1 = csub(x0, t);
        t = cmul(wA, x3); float2 b2 = cadd(x2, t), b3 = csub(x2, t);
        t = cmul(wA, x5); float2 b4 = cadd(x4, t), b5 = csub(x4, t);
        t = cmul(wA, x7); float2 b6 = cadd(x6, t), b7 = csub(x6, t);
        float2 wBi = make_float2(-sg * wB.y, sg * wB.x);
        t = cmul(wB, b2);  float2 c0 = cadd(b0, t), c2 = csub(b0, t);
        t = cmul(wBi, b3); float2 c1 = cadd(b1, t), c3 = csub(b1, t);
        t = cmul(wB, b6);  float2 c4 = cadd(b4, t), c6 = csub(b4, t);
        t = cmul(wBi, b7); float2 c5 = cadd(b5, t), c7 = csub(b5, t);
        float2 e1 = make_float2(s2, sg * s2);
        float2 e3 = make_float2(-s2, sg * s2);
        float2 w1 = cmul(wC, e1);
        float2 w2_ = make_float2(-sg * wC.y, sg * wC.x);
        float2 w3 = cmul(wC, e3);
        t = cmul(wC, c4);  d[swz(i0)]         = cadd(c0, t); d[swz(i0 + 4 * M)] = csub(c0, t);
        t = cmul(w1, c5);  d[swz(i0 + M)]     = cadd(c1, t); d[swz(i0 + 5 * M)] = csub(c1, t);
        t = cmul(w2_, c6); d[swz(i0 + 2 * M)] = cadd(c2, t); d[swz(i0 + 6 * M)] = csub(c2, t);
        t = cmul(w3, c7);  d[swz(i0 + 3 * M)] = cadd(c3, t); d[swz(i0 + 7 * M)] = csub(c3, t);
    }
    __syncthreads();
}

// Stage 1: [cauchy 2pt/thread, v11-real tables] ++ [transpose u->ut2 packed] ++ [skip].
__global__ __launch_bounds__(256, 8) void stage1_kernel(
    const float* __restrict__ u,
    const float* __restrict__ B_ri, const float* __restrict__ C_ri,
    const float* __restrict__ D,
    const float* __restrict__ Lambda_ri, const float* __restrict__ P_ri,
    const float* __restrict__ step,
    float2* __restrict__ at_g, float2* __restrict__ ut2, float* __restrict__ skip) {
    __shared__ float4 smem4[264];  // union: cauchy tabAB[128]+v11[64] / transpose tile 4224B
    const int bid = blockIdx.x;
    const int tid = threadIdx.x;

    if (bid < CAU_BLOCKS) {
        // ---- Cauchy: h = bid>>3; thread handles l = lbase + p*2048, p=0,1.
        // v11 = conj(P)*P = |P|^2 is REAL -> k11 is a real-weighted sum (2 fma, not 4)
        // and tables shrink to 2x b128 + 1x b32 per n.
        float* v11f = (float*)(smem4 + 128);  // [64]
        const int h = bid >> 3;
        if (tid < NN) {
            int n = tid;
            float2 C = ((const float2*)C_ri)[h * NN + n];
            float2 Bv = ((const float2*)B_ri)[h * NN + n];
            float2 P = ((const float2*)P_ri)[h * NN + n];
            float2 lam = ((const float2*)Lambda_ri)[h * NN + n];
            float2 Cc = make_float2(C.x, -C.y);
            float2 Pc = make_float2(P.x, -P.y);
            float2 v00 = cmul(Cc, Bv);
            float2 v01 = cmul(Cc, P);
            float2 v10 = cmul(Pc, Bv);
            smem4[2 * n + 0] = make_float4(lam.x, lam.y, v00.x, v00.y);
            smem4[2 * n + 1] = make_float4(v01.x, v01.y, v10.x, v10.y);
            v11f[n] = P.x * P.x + P.y * P.y;
        }
        __syncthreads();

        const int lbase = ((bid & 7) << 8) | tid;  // [0, 2048)
        const float two_over_step = 2.0f / step[0];
        float gr[2], gi[2], ccx[2], ccy[2];
#pragma unroll
        for (int p = 0; p < 2; ++p) {
            int l = lbase + p * 2048;
            // libm sincosf: at l=2048 the fp32-pi inexactness keeps 1+z away from
            // exactly 0 (matches reference). DO NOT replace with HW sin/cos.
            double th = -6.283185307179586476925286766559 * (double)l / (double)LL;
            float sn, cs;
            sincosf((float)th, &sn, &cs);
            float dr = 1.0f + cs, di = sn;
            float inv = __builtin_amdgcn_rcpf(dr * dr + di * di);
            float nr = 1.0f - cs, ni = -sn;
            gr[p] = two_over_step * (nr * dr + ni * di) * inv;
            gi[p] = two_over_step * (ni * dr - nr * di) * inv;
            ccx[p] = 2.0f * dr * inv;
            ccy[p] = -2.0f * di * inv;
        }

        float2 k00[2], k01[2], k10[2], k11[2];
#pragma unroll
        for (int p = 0; p < 2; ++p) {
            k00[p] = make_float2(0.f, 0.f);
            k01[p] = make_float2(0.f, 0.f);
            k10[p] = make_float2(0.f, 0.f);
            k11[p] = make_float2(0.f, 0.f);
        }
#pragma unroll 4
        for (int n = 0; n < NN; ++n) {
            float4 tA = smem4[2 * n + 0];
            float4 tB = smem4[2 * n + 1];
            float w11 = v11f[n];
#pragma unroll
            for (int p = 0; p < 2; ++p) {
                float ar = gr[p] - tA.x, ai = gi[p] - tA.y;
                float id = __builtin_amdgcn_rcpf(ar * ar + ai * ai);
                float2 r = make_float2(ar * id, -ai * id);
                k00[p] = cadd(k00[p], cmul(make_float2(tA.z, tA.w), r));
                k01[p] = cadd(k01[p], cmul(make_float2(tB.x, tB.y), r));
                k10[p] = cadd(k10[p], cmul(make_float2(tB.z, tB.w), r));
                k11[p].x += w11 * r.x;
                k11[p].y += w11 * r.y;
            }
        }
#pragma unroll
        for (int p = 0; p < 2; ++p) {
            float wr = 1.0f + k11[p].x, wi = k11[p].y;
            float iw = __builtin_amdgcn_rcpf(wr * wr + wi * wi);
            float2 winv = make_float2(wr * iw, -wi * iw);
            float2 t = cmul(cmul(k01[p], winv), k10[p]);
            float2 at = cmul(make_float2(ccx[p], ccy[p]),
                             make_float2(k00[p].x - t.x, k00[p].y - t.y));
            at_g[(size_t)h * LL + lbase + p * 2048] = at;
        }
    } else if (bid < CAU_BLOCKS + TRU_BLOCKS) {
        // ---- Transpose: u [B,L,H] -> ut2 [B,64,L] (packed float2 h-pairs) ----
        float* tile = (float*)smem4;  // [32][33]
        int tb = bid - CAU_BLOCKS;
        int b = tb >> 9;
        int hq = (tb >> 7) & 3;
        int h0 = hq * 32;
        int l0 = (tb & 127) * 32;
        int tx = tid & 31, ty = tid >> 5;  // ty 0..7
        const float* up = u + (size_t)b * LL * HH;
        for (int i = ty; i < 32; i += 8)
            tile[i * 33 + tx] = up[(size_t)(l0 + i) * HH + h0 + tx];
        __syncthreads();
        float2* utp = ut2 + (size_t)b * 64 * LL;
#pragma unroll
        for (int i = ty; i < 16; i += 8) {
            int c = (h0 >> 1) + i;
            float2 v = make_float2(tile[tx * 33 + 2 * i], tile[tx * 33 + 2 * i + 1]);
            utp[(size_t)c * LL + l0 + tx] = v;
        }
    } else {
        // ---- Skip: skip[row] = sum_h u[row,h]*D[h]; 1 row per 64-lane wave ----
        int sb = bid - (CAU_BLOCKS + TRU_BLOCKS);  // [0, 8192)
        int wid = tid >> 6, lane = tid & 63;
        int row = sb * 4 + wid;
        const float* ur = u + (size_t)row * HH;
        float v = ur[lane] * D[lane] + ur[lane + 64] * D[lane + 64];
        for (int off = 32; off > 0; off >>= 1) v += __shfl_down(v, off, 64);
        if (lane == 0) skip[row] = v;
    }
}

// Kernel A2: per h — scatter-load at -> IFFT4096 (dit_f8 x4) -> fused
// {scale+pad+head-r2} -> FFT8192 (dif_f8 x4) -> permuted K store.
__global__ __launch_bounds__(1024) void kfreq_kernel(const float2* __restrict__ at_g,
                                                     float2* __restrict__ KfP) {
    __shared__ float2 sm[NFFT];  // 64 KB
    const int h = blockIdx.x;
    const int tid = threadIdx.x;
    const float2* ap = at_g + (size_t)h * LL;
#pragma unroll
    for (int it = 0; it < 4; ++it) {
        int t = tid + it * 1024;
        int l = ((t & 63) << 6) | (t >> 6);          // low6<->high6 swap
        sm[swz((int)(__brev((unsigned)l) >> 20))] = ap[l];
    }
    __syncthreads();

    dit_f8<1>(sm, 4096, tid, 1024, +1.f);
    dit_f8<8>(sm, 4096, tid, 1024, +1.f);
    dit_f8<64>(sm, 4096, tid, 1024, +1.f);
    dit_f8<512>(sm, 4096, tid, 1024, +1.f);

    const float inv8192 = 1.0f / 8192.0f;
    for (int t = tid; t < 4096; t += 1024) {
        float kv = sm[swz(t)].x * (1.0f / 4096.0f);
        float2 w = twid((float)t * inv8192, -1.f);
        sm[swz(t)] = make_float2(kv, 0.f);
        sm[swz(t + 4096)] = make_float2(kv * w.x, kv * w.y);
    }
    __syncthreads();

    dif_f8<512>(sm, 8192, tid, 1024, -1.f);
    dif_f8<64>(sm, 8192, tid, 1024, -1.f);
    dif_f8<8>(sm, 8192, tid, 1024, -1.f);
    dif_f8<1>(sm, 8192, tid, 1024, -1.f);

    float2* kfp = KfP + (size_t)h * KSTR;
    for (int t = tid; t <= 4096; t += 1024) kfp[t] = sm[swz(brev13(kkmap(t)))];
}

// Kernel C: two-for-one conv — packed float2 input, half2 output.
__global__ __launch_bounds__(1024) void conv_fft_kernel(const float2* __restrict__ ut2,
                                                        const float2* __restrict__ KfP,
                                                        __half2* __restrict__ yt2) {
    __shared__ float2 sm[NFFT];  // 64 KB
    const int b = blockIdx.x >> 6;
    const int c = blockIdx.x & 63;
    const int h0 = 2 * c, h1 = 2 * c + 1;
    const int tid = threadIdx.x;
    const float2* up2 = ut2 + ((size_t)b * 64 + c) * LL;
    const float inv8192 = 1.0f / 8192.0f;

    // fused load + head radix-2 DIF stage (upper half of input is zero)
    for (int i = tid; i < 4096; i += 1024) {
        float2 a = up2[i];
        float2 w = twid((float)i * inv8192, -1.f);
        sm[swz(i)] = a;
        sm[swz(i + 4096)] = cmul(w, a);
    }
    __syncthreads();

    dif_f8<512>(sm, 8192, tid, 1024, -1.f);
    dif_f8<64>(sm, 8192, tid, 1024, -1.f);
    dif_f8<8>(sm, 8192, tid, 1024, -1.f);
    dif_f8<1>(sm, 8192, tid, 1024, -1.f);

    const float2* kf0 = KfP + (size_t)h0 * KSTR;
    const float2* kf1 = KfP + (size_t)h1 * KSTR;
    for (int t = tid; t <= 4096; t += 1024) {
        int kk = kkmap(t);
        bool self = (kk == 0) || (kk == 4096);
        int p = swz(brev13(kk));
        int q = self ? p : swz(brev13(NFFT - kk));
        float2 K0 = kf0[t];
        float2 K1 = kf1[t];
        float2 Zp = sm[p];
        float2 Zq = sm[q];
        float2 U0 = make_float2(0.5f * (Zp.x + Zq.x), 0.5f * (Zp.y - Zq.y));
        float2 U1 = make_float2(0.5f * (Zp.y + Zq.y), 0.5f * (Zq.x - Zp.x));
        float2 A = cmul(U0, K0);
        float2 C = cmul(U1, K1);
        sm[p] = make_float2(A.x - C.y, A.y + C.x);             // W[k]   = A + iC
        if (!self) sm[q] = make_float2(A.x + C.y, C.x - A.y);  // W[N-k] = conj(A - iC)
    }
    __syncthreads();

    dit_f8<1>(sm, 8192, tid, 1024, +1.f);
    dit_f8<8>(sm, 8192, tid, 1024, +1.f);
    dit_f8<64>(sm, 8192, tid, 1024, +1.f);
    dit_f8<512>(sm, 8192, tid, 1024, +1.f);

    // fused tail radix-2 DIT stage + 1/N scale + packed half2 store
    __half2* yp = yt2 + ((size_t)b * 64 + c) * LL;
    const float invN = 1.0f / (float)NFFT;
    for (int x = tid; x < 4096; x += 1024) {
        float2 w = twid((float)x * inv8192, +1.f);
        float2 a = sm[swz(x)];
        float2 bb = cmul(w, sm[swz(x + 4096)]);
        yp[x] = __floats2half2_rn((a.x + bb.x) * invN, (a.y + bb.y) * invN);
    }
}

// Kernel D: transpose yt2 [B,64,L] (half2) -> y [B,L,H] fp32, add skip[b,l].
__global__ __launch_bounds__(256) void transpose_y_kernel(const __half2* __restrict__ yt2,
                                                          const float* __restrict__ skip,
                                                          float* __restrict__ y) {
    __shared__ __half2 tile[32 * 17];
    int b = blockIdx.z;
    int c0 = blockIdx.x * 16;  // 16 half2 pairs = 32 h
    int l0 = blockIdx.y * 32;
    int tx = threadIdx.x, ty = threadIdx.y;  // 32 x 8
    const __half2* ytp = yt2 + (size_t)b * 64 * LL;
    const float* skp = skip + (size_t)b * LL;
    float* yp = y + (size_t)b * LL * HH;
    for (int i = ty; i < 16; i += 8)
        tile[tx * 17 + i] = ytp[(size_t)(c0 + i) * LL + l0 + tx];
    __syncthreads();
    int h0 = c0 * 2;
    for (int i = ty; i < 32; i += 8) {
        int l = l0 + i;
        float sk = skp[l];
        float2 f = __half22float2(tile[i * 17 + (tx >> 1)]);
        float v = (tx & 1) ? f.y : f.x;
        yp[(size_t)l * HH + h0 + tx] = v + sk;
    }
}

extern "C" void kernel_launch(void* const* d_in, const int* in_sizes, int n_in,
                              void* d_out, int out_size, void* d_ws, size_t ws_size,
                              hipStream_t stream) {
    const float* u = (const float*)d_in[0];
    const float* B_ri = (const float*)d_in[1];
    const float* C_ri = (const float*)d_in[2];
    const float* D = (const float*)d_in[3];
    const float* Lambda_ri = (const float*)d_in[4];
    const float* P_ri = (const float*)d_in[5];
    const float* step = (const float*)d_in[6];
    float* out = (float*)d_out;

    char* ws = (char*)d_ws;
    float2* KfP = (float2*)ws;                              // ~4.2 MB @ 0
    float* skip = (float*)(ws + (size_t)6 * 1024 * 1024);   // 128 KB @ 6 MB
    float2* ut2 = (float2*)(ws + (size_t)8 * 1024 * 1024);  // 16 MB @ 8 MB
    char* hi = ws + (size_t)24 * 1024 * 1024;               // 8 MB region @ 24 MB
    // at_g (4 MB) aliases the yt2 region: written by stage1, consumed by kfreq
    // before conv overwrites it with yt2 (stream-serial).
    float2* at_g = (float2*)hi;
    __half2* yt2 = (__half2*)hi;

    stage1_kernel<<<dim3(CAU_BLOCKS + TRU_BLOCKS + SKP_BLOCKS), dim3(256), 0, stream>>>(
        u, B_ri, C_ri, D, Lambda_ri, P_ri, step, at_g, ut2, skip);
    kfreq_kernel<<<dim3(HH), dim3(1024), 0, stream>>>(at_g, KfP);
    conv_fft_kernel<<<dim3(BB * HH / 2), dim3(1024), 0, stream>>>(ut2, KfP, yt2);
    transpose_y_kernel<<<dim3(HH / 32, LL / 32, BB), dim3(32, 8), 0, stream>>>(yt2, skip, out);
}